// Round 2
// 328.621 us; speedup vs baseline: 1.0748x; 1.0748x over previous
//
#include <hip/hip_runtime.h>

// multi_SelfAttention on MI355X (gfx950). Inputs fp32 (runtime-detected);
// bf16 MFMA compute; output dtype per flag.
// convert -> proj1 -> proj2 (Q pre-scaled 0.125*log2e) -> flash attn -> proj3.
// r10: r9's 32x32x16 structure, but the cross-half P exchange is done with
// __shfl_xor(32) + select instead of raw v_permlane32_swap_b32 asm (r9 failed
// at absmax 0.147 ~= the signature of a half-misrouted P; the permlane asm is
// the only HW-unverified link in the chain). Everything else identical to r9:
// S^T = mfma(K,Q) -> lane-local softmax row (q = lane&31), P packed bf16 in
// registers (no Ps LDS buffer), O^T accumulation (per-lane rescale + 1/l),
// V transpose staged as packed j-pair b32 stores, defer-max THR=8, LDS 24 KB.

typedef __bf16 bf16x8 __attribute__((ext_vector_type(8)));
typedef __bf16 bf16x4 __attribute__((ext_vector_type(4)));
typedef __bf16 bf16x2 __attribute__((ext_vector_type(2)));
typedef float floatx4 __attribute__((ext_vector_type(4)));
typedef float floatx16 __attribute__((ext_vector_type(16)));
typedef unsigned int uintx4 __attribute__((ext_vector_type(4)));

#define LDP 72  // padded stride for GEMM A tiles only

// 64-stride tile swizzle: 16B-chunk XOR; bank-uniform for row-major b128
// reads at fixed col, b128 row-staging writes, and b32 transpose stores.
#define SW64(row, col) (((row) << 6) | (((((col) >> 3) ^ ((row) & 7) ^ (((row) >> 3) & 7)) << 3) | ((col) & 7)))

#if __has_builtin(__builtin_amdgcn_exp2f)
__device__ __forceinline__ float fast_exp2(float x) { return __builtin_amdgcn_exp2f(x); }
#else
__device__ __forceinline__ float fast_exp2(float x) { return exp2f(x); }
#endif

__device__ __forceinline__ unsigned int pack_bf16(float lo, float hi) {
    bf16x2 w; w[0] = (__bf16)lo; w[1] = (__bf16)hi;
    return __builtin_bit_cast(unsigned int, w);
}
__device__ __forceinline__ unsigned int pack2(__bf16 lo, __bf16 hi) {
    bf16x2 w; w[0] = lo; w[1] = hi;
    return __builtin_bit_cast(unsigned int, w);
}
// Cross-half exchange: on return X = {hl0: X@hl0, hl1: Y@hl0} (word w),
// Y = {hl0: X@hl1, hl1: Y@hl1} (word w+2). Definitionally-correct shfl form.
__device__ __forceinline__ void xchg(unsigned int& X, unsigned int& Y, int hl) {
    unsigned int sX = (unsigned int)__shfl_xor((int)X, 32);
    unsigned int sY = (unsigned int)__shfl_xor((int)Y, 32);
    unsigned int lo = hl ? sY : X;
    unsigned int hi = hl ? Y : sX;
    X = lo; Y = hi;
}
__device__ __forceinline__ bf16x8 frag4(unsigned int a, unsigned int b, unsigned int c, unsigned int d) {
    uintx4 u; u[0] = a; u[1] = b; u[2] = c; u[3] = d;
    return __builtin_bit_cast(bf16x8, u);
}

// ---------------------------------------------------------------------------
__global__ void detect_dtype(const unsigned short* __restrict__ z, int* __restrict__ flag) {
    __shared__ int cnt;
    if (threadIdx.x == 0) cnt = 0;
    __syncthreads();
    int local = 0;
    for (int i = threadIdx.x; i < 16384; i += 256) {
        unsigned int u = (unsigned int)z[i] << 16;
        float x = __uint_as_float(u);
        float ax = fabsf(x);
        if (!(ax <= 1024.0f) || (x != 0.0f && ax < 1e-20f)) local++;
    }
    atomicAdd(&cnt, local);
    __syncthreads();
    if (threadIdx.x == 0) *flag = (cnt > 1310) ? 1 : 0;
}

// ---------------------------------------------------------------------------
struct ConvArgs { const void* src[12]; int n[12]; int off[12]; };

__global__ void convert_inputs(ConvArgs a, __bf16* __restrict__ cv, const int* __restrict__ flag,
                               int base_k) {
    const int k = blockIdx.y + base_k;
    const int i = (blockIdx.x * 256 + threadIdx.x) * 8;
    if (i >= a.n[k]) return;
    __bf16* dst = cv + a.off[k] + i;
    if (*flag) {
        const float* s = (const float*)a.src[k] + i;
        float4 f0 = *(const float4*)s;
        float4 f1 = *(const float4*)(s + 4);
        bf16x8 v;
        v[0] = (__bf16)f0.x; v[1] = (__bf16)f0.y; v[2] = (__bf16)f0.z; v[3] = (__bf16)f0.w;
        v[4] = (__bf16)f1.x; v[5] = (__bf16)f1.y; v[6] = (__bf16)f1.z; v[7] = (__bf16)f1.w;
        *(bf16x8*)dst = v;
    } else {
        *(bf16x8*)dst = *(const bf16x8*)((const __bf16*)a.src[k] + i);
    }
}

// ---------------------------------------------------------------------------
// Tiled GEMM: C[M,N] = (A@B + bias) * out_scale, bf16 in, fp32 acc.
// ---------------------------------------------------------------------------
__global__ __launch_bounds__(256) void gemm_bias(
    const __bf16* __restrict__ A0, const __bf16* __restrict__ A1, const __bf16* __restrict__ A2,
    const __bf16* __restrict__ B0, const __bf16* __restrict__ B1, const __bf16* __restrict__ B2,
    const __bf16* __restrict__ bias0, const __bf16* __restrict__ bias1, const __bf16* __restrict__ bias2,
    void* __restrict__ C0, void* __restrict__ C1, void* __restrict__ C2,
    int M, int N, int K, int has_bias, const int* flagp,
    float os0, float os1, float os2)
{
    const int zsel = blockIdx.z;
    const __bf16* A = (zsel == 0) ? A0 : (zsel == 1) ? A1 : A2;
    const __bf16* B = (zsel == 0) ? B0 : (zsel == 1) ? B1 : B2;
    const __bf16* bias = (zsel == 0) ? bias0 : (zsel == 1) ? bias1 : bias2;
    void* C = (zsel == 0) ? C0 : (zsel == 1) ? C1 : C2;
    const float oscale = (zsel == 0) ? os0 : (zsel == 1) ? os1 : os2;
    const int out_fp32 = flagp ? *flagp : 0;

    const int m0 = blockIdx.x * 128;
    const int n0 = blockIdx.y * 64;
    const int tid = threadIdx.x;
    const int wave = tid >> 6;
    const int ln = tid & 15;
    const int quad = (tid >> 4) & 3;

    __shared__ __bf16 As[128 * LDP];
    __shared__ __bf16 Bts[64 * 64];   // SW64-swizzled [n][k]

    floatx4 acc[2][4] = {};

    for (int k0 = 0; k0 < K; k0 += 64) {
        __syncthreads();
        for (int i = tid; i < 1024; i += 256) {
            int r = i >> 3, c8 = (i & 7) << 3;
            *(bf16x8*)&As[r * LDP + c8] = *(const bf16x8*)&A[(m0 + r) * K + k0 + c8];
        }
        for (int i = tid; i < 512; i += 256) {
            int kk = i >> 3, a8 = (i & 7) << 3;
            bf16x8 v = *(const bf16x8*)&B[(k0 + kk) * N + n0 + a8];
            #pragma unroll
            for (int j = 0; j < 8; j++) Bts[SW64(a8 + j, kk)] = v[j];
        }
        __syncthreads();
        #pragma unroll
        for (int ks = 0; ks < 2; ks++) {
            bf16x8 a[2], b[4];
            a[0] = *(const bf16x8*)&As[(wave * 32 + ln) * LDP + ks * 32 + quad * 8];
            a[1] = *(const bf16x8*)&As[(wave * 32 + 16 + ln) * LDP + ks * 32 + quad * 8];
            #pragma unroll
            for (int nt = 0; nt < 4; nt++)
                b[nt] = *(const bf16x8*)&Bts[SW64(nt * 16 + ln, ks * 32 + quad * 8)];
            #pragma unroll
            for (int rt = 0; rt < 2; rt++)
                #pragma unroll
                for (int nt = 0; nt < 4; nt++)
                    acc[rt][nt] = __builtin_amdgcn_mfma_f32_16x16x32_bf16(a[rt], b[nt], acc[rt][nt], 0, 0, 0);
        }
    }
    #pragma unroll
    for (int rt = 0; rt < 2; rt++) {
        const int row = m0 + wave * 32 + rt * 16 + quad * 4;
        #pragma unroll
        for (int nt = 0; nt < 4; nt++) {
            const int col = n0 + nt * 16 + ln;
            float bv = has_bias ? (float)bias[col] : 0.0f;
            #pragma unroll
            for (int r = 0; r < 4; r++) {
                float val = (acc[rt][nt][r] + bv) * oscale;
                if (out_fp32) ((float*)C)[(row + r) * N + col] = val;
                else ((__bf16*)C)[(row + r) * N + col] = (__bf16)val;
            }
        }
    }
}

// ---------------------------------------------------------------------------
// Flash attention r10 (32x32 S^T / O^T formulation, in-register P):
//  S^T[j][q] = mfma_32x32x16(A=K-frag, B=Q-frag): lane q = ln&31, 16 j/reg/jt.
//  Softmax per-lane scalar; full-j reduce = own-32 tree + shfl_xor(32).
//  P -> bf16 pack (pairs) + shfl_xor(32)/select -> PV B-frags, NO LDS round
//  trip. O^T[d][q] = mfma(A=VTs rows b128, B=P-frag): C col = q = ln&31, so
//  rescale and 1/l are per-lane (no shuffles). V transpose staged as j-pair
//  b32 stores. LDS 24 KB (Ks 8K single-buf + VTs 2x8K dbuf). K/V(t+1) global
//  loads issued at iteration top.
//  XCD grid: bh=blockIdx.x -> XCD=bh%8 -> per-XCD K/V set ~4MB = L2.
// ---------------------------------------------------------------------------
__global__ __launch_bounds__(256, 3) void attn_kernel(
    const __bf16* __restrict__ Qg, const __bf16* __restrict__ Kg,
    const __bf16* __restrict__ Vg, __bf16* __restrict__ Og)
{
    const int bh = blockIdx.x;
    const int b = bh >> 4, h = bh & 15;
    const int q0 = blockIdx.y * 128;
    const int base = b * 2048 * 1024 + h * 64;
    const int tid = threadIdx.x;
    const int wave = tid >> 6, ln = tid & 63;
    const int l31 = ln & 31, hl = ln >> 5;    // lane-in-32, lane half
    const int h8 = hl * 8;

    __shared__ __bf16 Ks[64 * 64];        // 8 KB, single buffer, SW64 [j][k]
    __shared__ __bf16 VTs[2][64 * 64];    // 16 KB, double buffer, SW64 [d][j]

    // Q fragments (B-operand of S^T): lane n=q=l31, k = ks*16 + h8 + e
    bf16x8 qf[4];
    #pragma unroll
    for (int ks = 0; ks < 4; ks++)
        qf[ks] = *(const bf16x8*)&Qg[base + (q0 + wave * 32 + l31) * 1024 + ks * 16 + h8];

    const int kr = tid >> 3, kc = (tid & 7) << 3;   // K staging: rows kr, kr+32
    const int vr2 = (tid >> 3) * 2, vc = (tid & 7) << 3;  // V staging: row pair

    {   // tile 0 (published by barrier A at t=0)
        bf16x8 ka = *(const bf16x8*)&Kg[base + kr * 1024 + kc];
        bf16x8 kb = *(const bf16x8*)&Kg[base + (kr + 32) * 1024 + kc];
        bf16x8 va = *(const bf16x8*)&Vg[base + vr2 * 1024 + vc];
        bf16x8 vb = *(const bf16x8*)&Vg[base + (vr2 + 1) * 1024 + vc];
        *(bf16x8*)&Ks[SW64(kr, kc)] = ka;
        *(bf16x8*)&Ks[SW64(kr + 32, kc)] = kb;
        #pragma unroll
        for (int j = 0; j < 8; j++)
            *(unsigned int*)&VTs[0][SW64(vc + j, vr2)] = pack2(va[j], vb[j]);
    }

    floatx16 o_acc[2] = {};
    float m_i = -1e30f, l_i = 0.0f;

    for (int t = 0; t < 32; t++) {
        const int cur = t & 1;
        bf16x8 nka, nkb, nva, nvb;          // K/V(t+1) register prefetch
        if (t < 31) {
            const int kvn = (t + 1) * 64;
            nka = *(const bf16x8*)&Kg[base + (kvn + kr) * 1024 + kc];
            nkb = *(const bf16x8*)&Kg[base + (kvn + kr + 32) * 1024 + kc];
            nva = *(const bf16x8*)&Vg[base + (kvn + vr2) * 1024 + vc];
            nvb = *(const bf16x8*)&Vg[base + (kvn + vr2 + 1) * 1024 + vc];
        }
        __syncthreads();  // A: Ks(t), VTs[cur](t) visible

        // ---- S^T = K · Q^T: lane q=l31; j = (r&3)+8*(r>>2)+4*hl (+32 for s1)
        floatx16 sv[2] = {};
        #pragma unroll
        for (int ks = 0; ks < 4; ks++) {
            bf16x8 a0 = *(const bf16x8*)&Ks[SW64(l31, ks * 16 + h8)];
            bf16x8 a1 = *(const bf16x8*)&Ks[SW64(32 + l31, ks * 16 + h8)];
            sv[0] = __builtin_amdgcn_mfma_f32_32x32x16_bf16(a0, qf[ks], sv[0], 0, 0, 0);
            sv[1] = __builtin_amdgcn_mfma_f32_32x32x16_bf16(a1, qf[ks], sv[1], 0, 0, 0);
        }

        // ---- softmax for q=l31 over 64 j: own-32 tree + partner half
        float m8[8];
        #pragma unroll
        for (int r = 0; r < 8; r++)
            m8[r] = fmaxf(fmaxf(sv[0][r], sv[0][r + 8]), fmaxf(sv[1][r], sv[1][r + 8]));
        float mx = fmaxf(fmaxf(fmaxf(m8[0], m8[4]), fmaxf(m8[1], m8[5])),
                         fmaxf(fmaxf(m8[2], m8[6]), fmaxf(m8[3], m8[7])));
        mx = fmaxf(mx, __shfl_xor(mx, 32));

        if (__any(mx > m_i + 8.0f)) {       // defer-max: rescale only on big jumps
            float m_new = fmaxf(m_i, mx);
            float alpha = fast_exp2(m_i - m_new);
            m_i = m_new;
            l_i *= alpha;
            #pragma unroll
            for (int dt = 0; dt < 2; dt++)
                #pragma unroll
                for (int r = 0; r < 16; r++) o_acc[dt][r] *= alpha;
        }

        float p0[16], p1[16];
        #pragma unroll
        for (int r = 0; r < 16; r++) p0[r] = fast_exp2(sv[0][r] - m_i);
        #pragma unroll
        for (int r = 0; r < 16; r++) p1[r] = fast_exp2(sv[1][r] - m_i);
        float rsA = 0.f, rsB = 0.f, rsC = 0.f, rsD = 0.f;
        #pragma unroll
        for (int r = 0; r < 16; r += 4) {
            rsA += p0[r]; rsB += p0[r + 1]; rsC += p0[r + 2]; rsD += p0[r + 3];
            rsA += p1[r]; rsB += p1[r + 1]; rsC += p1[r + 2]; rsD += p1[r + 3];
        }
        float rs = (rsA + rsB) + (rsC + rsD);
        rs += __shfl_xor(rs, 32);
        l_i += rs;

        // ---- P -> bf16 B-frags in registers (pack pairs; shfl_xor exchange)
        bf16x8 pf0, pf1, pf2, pf3;
        {
            unsigned int A0 = pack_bf16(p0[0], p0[1]),  B0 = pack_bf16(p0[2], p0[3]);
            unsigned int C0 = pack_bf16(p0[4], p0[5]),  D0 = pack_bf16(p0[6], p0[7]);
            unsigned int A1 = pack_bf16(p0[8], p0[9]),  B1 = pack_bf16(p0[10], p0[11]);
            unsigned int C1 = pack_bf16(p0[12], p0[13]), D1 = pack_bf16(p0[14], p0[15]);
            xchg(A0, C0, hl); xchg(B0, D0, hl); xchg(A1, C1, hl); xchg(B1, D1, hl);
            pf0 = frag4(A0, B0, C0, D0);
            pf1 = frag4(A1, B1, C1, D1);
        }
        {
            unsigned int A0 = pack_bf16(p1[0], p1[1]),  B0 = pack_bf16(p1[2], p1[3]);
            unsigned int C0 = pack_bf16(p1[4], p1[5]),  D0 = pack_bf16(p1[6], p1[7]);
            unsigned int A1 = pack_bf16(p1[8], p1[9]),  B1 = pack_bf16(p1[10], p1[11]);
            unsigned int C1 = pack_bf16(p1[12], p1[13]), D1 = pack_bf16(p1[14], p1[15]);
            xchg(A0, C0, hl); xchg(B0, D0, hl); xchg(A1, C1, hl); xchg(B1, D1, hl);
            pf2 = frag4(A0, B0, C0, D0);
            pf3 = frag4(A1, B1, C1, D1);
        }

        __syncthreads();  // B: all Ks reads drained

        if (t < 31) {     // K(t+1) into single-buffered Ks, overlaps PV below
            *(bf16x8*)&Ks[SW64(kr, kc)] = nka;
            *(bf16x8*)&Ks[SW64(kr + 32, kc)] = nkb;
        }

        // ---- O^T += V^T · P^T  (A = VTs rows b128, B = P-frags in regs)
        #pragma unroll
        for (int js = 0; js < 4; js++) {
            bf16x8 av0 = *(const bf16x8*)&VTs[cur][SW64(l31, js * 16 + h8)];
            bf16x8 av1 = *(const bf16x8*)&VTs[cur][SW64(32 + l31, js * 16 + h8)];
            bf16x8 pb = (js == 0) ? pf0 : (js == 1) ? pf1 : (js == 2) ? pf2 : pf3;
            o_acc[0] = __builtin_amdgcn_mfma_f32_32x32x16_bf16(av0, pb, o_acc[0], 0, 0, 0);
            o_acc[1] = __builtin_amdgcn_mfma_f32_32x32x16_bf16(av1, pb, o_acc[1], 0, 0, 0);
        }

        if (t < 31) {     // V(t+1) transpose store (loads issued at iter top)
            const int nxt = cur ^ 1;
            #pragma unroll
            for (int j = 0; j < 8; j++)
                *(unsigned int*)&VTs[nxt][SW64(vc + j, vr2)] = pack2(nva[j], nvb[j]);
        }
    }

    // ---- epilogue: O^T lane holds q=l31, d = dt*32 + 8g + 4*hl + e
    float inv = 1.0f / l_i;
    const int orow = q0 + wave * 32 + l31;
    #pragma unroll
    for (int dt = 0; dt < 2; dt++)
        #pragma unroll
        for (int g = 0; g < 4; g++) {
            bf16x4 ov;
            #pragma unroll
            for (int e = 0; e < 4; e++) ov[e] = (__bf16)(o_acc[dt][g * 4 + e] * inv);
            *(bf16x4*)&Og[base + orow * 1024 + dt * 32 + g * 8 + hl * 4] = ov;
        }
}

// ---------------------------------------------------------------------------
extern "C" void kernel_launch(void* const* d_in, const int* in_sizes, int n_in,
                              void* d_out, int out_size, void* d_ws, size_t ws_size,
                              hipStream_t stream)
{
    int* flag = (int*)d_ws;
    __bf16* cv = (__bf16*)((char*)d_ws + 256);

    const int Z = 0, WQ = 8388608, WK = 8454144, WV = 8519680;
    const int FCQW = 8585216, FCKW = 8650752, FCVW = 8716288, FCOW = 8781824;
    const int FCQB = 9830400, FCKB = 9831424, FCVB = 9832448, FCOB = 9833472;
    __bf16* zb = cv + 10485760;
    __bf16* Qw = cv + 12582912;
    __bf16* Kw = Qw + 8388608;
    __bf16* Vw = Kw + 8388608;
    __bf16* Ow = cv + Z;  // reuse z-copy region (dead after proj1)

    detect_dtype<<<1, 256, 0, stream>>>((const unsigned short*)d_in[0], flag);

    ConvArgs ca;
    const int offs[12] = {Z, WQ, WK, WV, FCQW, FCQB, FCKW, FCKB, FCVW, FCVB, FCOW, FCOB};
    for (int i = 0; i < 12; i++) { ca.src[i] = d_in[i]; ca.n[i] = in_sizes[i]; ca.off[i] = offs[i]; }
    convert_inputs<<<dim3(4096, 1), 256, 0, stream>>>(ca, cv, flag, 0);
    convert_inputs<<<dim3(512, 11), 256, 0, stream>>>(ca, cv, flag, 1);

    gemm_bias<<<dim3(64, 1, 3), 256, 0, stream>>>(
        cv + Z, cv + Z, cv + Z, cv + WQ, cv + WK, cv + WV,
        cv + FCQB, cv + FCQB, cv + FCQB,
        zb, zb + 524288, zb + 1048576, 8192, 64, 1024, 0, nullptr,
        1.0f, 1.0f, 1.0f);

    const float QSC = 0.125f * 1.44269504088896f;  // fold 1/sqrt(dk) * log2(e) into Q
    gemm_bias<<<dim3(64, 16, 3), 256, 0, stream>>>(
        zb, zb + 524288, zb + 1048576,
        cv + FCQW, cv + FCKW, cv + FCVW, cv + FCQB, cv + FCKB, cv + FCVB,
        Qw, Kw, Vw, 8192, 1024, 64, 1, nullptr,
        QSC, 1.0f, 1.0f);

    attn_kernel<<<dim3(64, 16), 256, 0, stream>>>(Qw, Kw, Vw, Ow);

    gemm_bias<<<dim3(64, 16, 1), 256, 0, stream>>>(
        Ow, Ow, Ow, cv + FCOW, cv + FCOW, cv + FCOW, cv + FCOB, cv + FCOB, cv + FCOB,
        d_out, d_out, d_out, 8192, 1024, 1024, 1, flag,
        1.0f, 1.0f, 1.0f);
}

// Round 3
// 318.701 us; speedup vs baseline: 1.1083x; 1.0311x over previous
//
#include <hip/hip_runtime.h>

// multi_SelfAttention on MI355X (gfx950). Inputs fp32 (runtime-detected);
// bf16 MFMA compute; output dtype per flag.
// convert -> proj1 -> proj2 (Q pre-scaled 0.125*log2e) -> flash attn -> proj3.
// r11: r10 + (a) Ks double-buffered -> ONE __syncthreads per KV tile (was 2);
// writes always target the nxt buffer so the top-of-loop barrier is the only
// ordering needed. (b) cross-half P exchange via __builtin_amdgcn_permlane32_swap
// (HW-verified builtin, returns {vdst',vsrc'} == r10's shfl construction),
// guarded by __has_builtin with the proven shfl fallback. LDS 32 KB.

typedef __bf16 bf16x8 __attribute__((ext_vector_type(8)));
typedef __bf16 bf16x4 __attribute__((ext_vector_type(4)));
typedef __bf16 bf16x2 __attribute__((ext_vector_type(2)));
typedef float floatx4 __attribute__((ext_vector_type(4)));
typedef float floatx16 __attribute__((ext_vector_type(16)));
typedef unsigned int uintx4 __attribute__((ext_vector_type(4)));
typedef unsigned int uintx2 __attribute__((ext_vector_type(2)));

#define LDP 72  // padded stride for GEMM A tiles only

// 64-stride tile swizzle: 16B-chunk XOR; bank-uniform for row-major b128
// reads at fixed col, b128 row-staging writes, and b32 transpose stores.
#define SW64(row, col) (((row) << 6) | (((((col) >> 3) ^ ((row) & 7) ^ (((row) >> 3) & 7)) << 3) | ((col) & 7)))

#if __has_builtin(__builtin_amdgcn_exp2f)
__device__ __forceinline__ float fast_exp2(float x) { return __builtin_amdgcn_exp2f(x); }
#else
__device__ __forceinline__ float fast_exp2(float x) { return exp2f(x); }
#endif

__device__ __forceinline__ unsigned int pack_bf16(float lo, float hi) {
    bf16x2 w; w[0] = (__bf16)lo; w[1] = (__bf16)hi;
    return __builtin_bit_cast(unsigned int, w);
}
__device__ __forceinline__ unsigned int pack2(__bf16 lo, __bf16 hi) {
    bf16x2 w; w[0] = lo; w[1] = hi;
    return __builtin_bit_cast(unsigned int, w);
}
// Cross-half exchange: on return X = {hl0: X@hl0, hl1: Y@hl-partner} (word w),
// Y = {hl0: X@hl-partner, hl1: Y@hl1} (word w+2).
#if __has_builtin(__builtin_amdgcn_permlane32_swap)
__device__ __forceinline__ void xchg(unsigned int& X, unsigned int& Y, int) {
    uintx2 r = __builtin_amdgcn_permlane32_swap(X, Y, false, false);
    X = r[0]; Y = r[1];
}
#else
__device__ __forceinline__ void xchg(unsigned int& X, unsigned int& Y, int hl) {
    unsigned int sX = (unsigned int)__shfl_xor((int)X, 32);
    unsigned int sY = (unsigned int)__shfl_xor((int)Y, 32);
    unsigned int lo = hl ? sY : X;
    unsigned int hi = hl ? Y : sX;
    X = lo; Y = hi;
}
#endif
__device__ __forceinline__ bf16x8 frag4(unsigned int a, unsigned int b, unsigned int c, unsigned int d) {
    uintx4 u; u[0] = a; u[1] = b; u[2] = c; u[3] = d;
    return __builtin_bit_cast(bf16x8, u);
}

// ---------------------------------------------------------------------------
__global__ void detect_dtype(const unsigned short* __restrict__ z, int* __restrict__ flag) {
    __shared__ int cnt;
    if (threadIdx.x == 0) cnt = 0;
    __syncthreads();
    int local = 0;
    for (int i = threadIdx.x; i < 16384; i += 256) {
        unsigned int u = (unsigned int)z[i] << 16;
        float x = __uint_as_float(u);
        float ax = fabsf(x);
        if (!(ax <= 1024.0f) || (x != 0.0f && ax < 1e-20f)) local++;
    }
    atomicAdd(&cnt, local);
    __syncthreads();
    if (threadIdx.x == 0) *flag = (cnt > 1310) ? 1 : 0;
}

// ---------------------------------------------------------------------------
struct ConvArgs { const void* src[12]; int n[12]; int off[12]; };

__global__ void convert_inputs(ConvArgs a, __bf16* __restrict__ cv, const int* __restrict__ flag,
                               int base_k) {
    const int k = blockIdx.y + base_k;
    const int i = (blockIdx.x * 256 + threadIdx.x) * 8;
    if (i >= a.n[k]) return;
    __bf16* dst = cv + a.off[k] + i;
    if (*flag) {
        const float* s = (const float*)a.src[k] + i;
        float4 f0 = *(const float4*)s;
        float4 f1 = *(const float4*)(s + 4);
        bf16x8 v;
        v[0] = (__bf16)f0.x; v[1] = (__bf16)f0.y; v[2] = (__bf16)f0.z; v[3] = (__bf16)f0.w;
        v[4] = (__bf16)f1.x; v[5] = (__bf16)f1.y; v[6] = (__bf16)f1.z; v[7] = (__bf16)f1.w;
        *(bf16x8*)dst = v;
    } else {
        *(bf16x8*)dst = *(const bf16x8*)((const __bf16*)a.src[k] + i);
    }
}

// ---------------------------------------------------------------------------
// Tiled GEMM: C[M,N] = (A@B + bias) * out_scale, bf16 in, fp32 acc.
// ---------------------------------------------------------------------------
__global__ __launch_bounds__(256) void gemm_bias(
    const __bf16* __restrict__ A0, const __bf16* __restrict__ A1, const __bf16* __restrict__ A2,
    const __bf16* __restrict__ B0, const __bf16* __restrict__ B1, const __bf16* __restrict__ B2,
    const __bf16* __restrict__ bias0, const __bf16* __restrict__ bias1, const __bf16* __restrict__ bias2,
    void* __restrict__ C0, void* __restrict__ C1, void* __restrict__ C2,
    int M, int N, int K, int has_bias, const int* flagp,
    float os0, float os1, float os2)
{
    const int zsel = blockIdx.z;
    const __bf16* A = (zsel == 0) ? A0 : (zsel == 1) ? A1 : A2;
    const __bf16* B = (zsel == 0) ? B0 : (zsel == 1) ? B1 : B2;
    const __bf16* bias = (zsel == 0) ? bias0 : (zsel == 1) ? bias1 : bias2;
    void* C = (zsel == 0) ? C0 : (zsel == 1) ? C1 : C2;
    const float oscale = (zsel == 0) ? os0 : (zsel == 1) ? os1 : os2;
    const int out_fp32 = flagp ? *flagp : 0;

    const int m0 = blockIdx.x * 128;
    const int n0 = blockIdx.y * 64;
    const int tid = threadIdx.x;
    const int wave = tid >> 6;
    const int ln = tid & 15;
    const int quad = (tid >> 4) & 3;

    __shared__ __bf16 As[128 * LDP];
    __shared__ __bf16 Bts[64 * 64];   // SW64-swizzled [n][k]

    floatx4 acc[2][4] = {};

    for (int k0 = 0; k0 < K; k0 += 64) {
        __syncthreads();
        for (int i = tid; i < 1024; i += 256) {
            int r = i >> 3, c8 = (i & 7) << 3;
            *(bf16x8*)&As[r * LDP + c8] = *(const bf16x8*)&A[(m0 + r) * K + k0 + c8];
        }
        for (int i = tid; i < 512; i += 256) {
            int kk = i >> 3, a8 = (i & 7) << 3;
            bf16x8 v = *(const bf16x8*)&B[(k0 + kk) * N + n0 + a8];
            #pragma unroll
            for (int j = 0; j < 8; j++) Bts[SW64(a8 + j, kk)] = v[j];
        }
        __syncthreads();
        #pragma unroll
        for (int ks = 0; ks < 2; ks++) {
            bf16x8 a[2], b[4];
            a[0] = *(const bf16x8*)&As[(wave * 32 + ln) * LDP + ks * 32 + quad * 8];
            a[1] = *(const bf16x8*)&As[(wave * 32 + 16 + ln) * LDP + ks * 32 + quad * 8];
            #pragma unroll
            for (int nt = 0; nt < 4; nt++)
                b[nt] = *(const bf16x8*)&Bts[SW64(nt * 16 + ln, ks * 32 + quad * 8)];
            #pragma unroll
            for (int rt = 0; rt < 2; rt++)
                #pragma unroll
                for (int nt = 0; nt < 4; nt++)
                    acc[rt][nt] = __builtin_amdgcn_mfma_f32_16x16x32_bf16(a[rt], b[nt], acc[rt][nt], 0, 0, 0);
        }
    }
    #pragma unroll
    for (int rt = 0; rt < 2; rt++) {
        const int row = m0 + wave * 32 + rt * 16 + quad * 4;
        #pragma unroll
        for (int nt = 0; nt < 4; nt++) {
            const int col = n0 + nt * 16 + ln;
            float bv = has_bias ? (float)bias[col] : 0.0f;
            #pragma unroll
            for (int r = 0; r < 4; r++) {
                float val = (acc[rt][nt][r] + bv) * oscale;
                if (out_fp32) ((float*)C)[(row + r) * N + col] = val;
                else ((__bf16*)C)[(row + r) * N + col] = (__bf16)val;
            }
        }
    }
}

// ---------------------------------------------------------------------------
// Flash attention r11 (32x32 S^T / O^T, in-register P, single-barrier loop):
//  S^T[j][q] = mfma_32x32x16(A=K-frag, B=Q-frag): lane q = ln&31, 16 j/reg/jt.
//  Softmax per-lane scalar; full-j reduce = own-32 tree + shfl_xor(32).
//  P -> bf16 pack (pairs) + permlane32_swap -> PV B-frags, NO LDS round trip.
//  O^T[d][q] = mfma(A=VTs rows b128, B=P-frag): per-lane rescale + 1/l.
//  BOTH Ks and VTs double-buffered: iter t reads buf[cur], writes buf[nxt];
//  one __syncthreads per iteration orders writes(t-1)->reads(t) and
//  reads(t-1)->writes(t). LDS 32 KB -> 4 blocks/CU (grid-limited anyway).
//  XCD grid: bh=blockIdx.x -> XCD=bh%8 -> per-XCD K/V set ~4MB = L2.
// ---------------------------------------------------------------------------
__global__ __launch_bounds__(256, 3) void attn_kernel(
    const __bf16* __restrict__ Qg, const __bf16* __restrict__ Kg,
    const __bf16* __restrict__ Vg, __bf16* __restrict__ Og)
{
    const int bh = blockIdx.x;
    const int b = bh >> 4, h = bh & 15;
    const int q0 = blockIdx.y * 128;
    const int base = b * 2048 * 1024 + h * 64;
    const int tid = threadIdx.x;
    const int wave = tid >> 6, ln = tid & 63;
    const int l31 = ln & 31, hl = ln >> 5;    // lane-in-32, lane half
    const int h8 = hl * 8;

    __shared__ __bf16 Ks[2][64 * 64];     // 16 KB, double buffer, SW64 [j][k]
    __shared__ __bf16 VTs[2][64 * 64];    // 16 KB, double buffer, SW64 [d][j]

    // Q fragments (B-operand of S^T): lane n=q=l31, k = ks*16 + h8 + e
    bf16x8 qf[4];
    #pragma unroll
    for (int ks = 0; ks < 4; ks++)
        qf[ks] = *(const bf16x8*)&Qg[base + (q0 + wave * 32 + l31) * 1024 + ks * 16 + h8];

    const int kr = tid >> 3, kc = (tid & 7) << 3;   // K staging: rows kr, kr+32
    const int vr2 = (tid >> 3) * 2, vc = (tid & 7) << 3;  // V staging: row pair

    {   // tile 0 (published by the t=0 barrier)
        bf16x8 ka = *(const bf16x8*)&Kg[base + kr * 1024 + kc];
        bf16x8 kb = *(const bf16x8*)&Kg[base + (kr + 32) * 1024 + kc];
        bf16x8 va = *(const bf16x8*)&Vg[base + vr2 * 1024 + vc];
        bf16x8 vb = *(const bf16x8*)&Vg[base + (vr2 + 1) * 1024 + vc];
        *(bf16x8*)&Ks[0][SW64(kr, kc)] = ka;
        *(bf16x8*)&Ks[0][SW64(kr + 32, kc)] = kb;
        #pragma unroll
        for (int j = 0; j < 8; j++)
            *(unsigned int*)&VTs[0][SW64(vc + j, vr2)] = pack2(va[j], vb[j]);
    }

    floatx16 o_acc[2] = {};
    float m_i = -1e30f, l_i = 0.0f;

    for (int t = 0; t < 32; t++) {
        const int cur = t & 1, nxt = cur ^ 1;
        bf16x8 nka, nkb, nva, nvb;          // K/V(t+1) register prefetch
        if (t < 31) {
            const int kvn = (t + 1) * 64;
            nka = *(const bf16x8*)&Kg[base + (kvn + kr) * 1024 + kc];
            nkb = *(const bf16x8*)&Kg[base + (kvn + kr + 32) * 1024 + kc];
            nva = *(const bf16x8*)&Vg[base + (kvn + vr2) * 1024 + vc];
            nvb = *(const bf16x8*)&Vg[base + (kvn + vr2 + 1) * 1024 + vc];
        }
        __syncthreads();  // writes(t-1) -> nxt_{t-1}=cur visible; reads(t-1) drained

        // ---- S^T = K · Q^T: lane q=l31; j = (r&3)+8*(r>>2)+4*hl (+32 for s1)
        floatx16 sv[2] = {};
        #pragma unroll
        for (int ks = 0; ks < 4; ks++) {
            bf16x8 a0 = *(const bf16x8*)&Ks[cur][SW64(l31, ks * 16 + h8)];
            bf16x8 a1 = *(const bf16x8*)&Ks[cur][SW64(32 + l31, ks * 16 + h8)];
            sv[0] = __builtin_amdgcn_mfma_f32_32x32x16_bf16(a0, qf[ks], sv[0], 0, 0, 0);
            sv[1] = __builtin_amdgcn_mfma_f32_32x32x16_bf16(a1, qf[ks], sv[1], 0, 0, 0);
        }

        // ---- softmax for q=l31 over 64 j: own-32 tree + partner half
        float m8[8];
        #pragma unroll
        for (int r = 0; r < 8; r++)
            m8[r] = fmaxf(fmaxf(sv[0][r], sv[0][r + 8]), fmaxf(sv[1][r], sv[1][r + 8]));
        float mx = fmaxf(fmaxf(fmaxf(m8[0], m8[4]), fmaxf(m8[1], m8[5])),
                         fmaxf(fmaxf(m8[2], m8[6]), fmaxf(m8[3], m8[7])));
        mx = fmaxf(mx, __shfl_xor(mx, 32));

        if (__any(mx > m_i + 8.0f)) {       // defer-max: rescale only on big jumps
            float m_new = fmaxf(m_i, mx);
            float alpha = fast_exp2(m_i - m_new);
            m_i = m_new;
            l_i *= alpha;
            #pragma unroll
            for (int dt = 0; dt < 2; dt++)
                #pragma unroll
                for (int r = 0; r < 16; r++) o_acc[dt][r] *= alpha;
        }

        float p0[16], p1[16];
        #pragma unroll
        for (int r = 0; r < 16; r++) p0[r] = fast_exp2(sv[0][r] - m_i);
        #pragma unroll
        for (int r = 0; r < 16; r++) p1[r] = fast_exp2(sv[1][r] - m_i);
        float rsA = 0.f, rsB = 0.f, rsC = 0.f, rsD = 0.f;
        #pragma unroll
        for (int r = 0; r < 16; r += 4) {
            rsA += p0[r]; rsB += p0[r + 1]; rsC += p0[r + 2]; rsD += p0[r + 3];
            rsA += p1[r]; rsB += p1[r + 1]; rsC += p1[r + 2]; rsD += p1[r + 3];
        }
        float rs = (rsA + rsB) + (rsC + rsD);
        rs += __shfl_xor(rs, 32);
        l_i += rs;

        // ---- P -> bf16 B-frags in registers (pack pairs; cross-half exchange)
        bf16x8 pf0, pf1, pf2, pf3;
        {
            unsigned int A0 = pack_bf16(p0[0], p0[1]),  B0 = pack_bf16(p0[2], p0[3]);
            unsigned int C0 = pack_bf16(p0[4], p0[5]),  D0 = pack_bf16(p0[6], p0[7]);
            unsigned int A1 = pack_bf16(p0[8], p0[9]),  B1 = pack_bf16(p0[10], p0[11]);
            unsigned int C1 = pack_bf16(p0[12], p0[13]), D1 = pack_bf16(p0[14], p0[15]);
            xchg(A0, C0, hl); xchg(B0, D0, hl); xchg(A1, C1, hl); xchg(B1, D1, hl);
            pf0 = frag4(A0, B0, C0, D0);
            pf1 = frag4(A1, B1, C1, D1);
        }
        {
            unsigned int A0 = pack_bf16(p1[0], p1[1]),  B0 = pack_bf16(p1[2], p1[3]);
            unsigned int C0 = pack_bf16(p1[4], p1[5]),  D0 = pack_bf16(p1[6], p1[7]);
            unsigned int A1 = pack_bf16(p1[8], p1[9]),  B1 = pack_bf16(p1[10], p1[11]);
            unsigned int C1 = pack_bf16(p1[12], p1[13]), D1 = pack_bf16(p1[14], p1[15]);
            xchg(A0, C0, hl); xchg(B0, D0, hl); xchg(A1, C1, hl); xchg(B1, D1, hl);
            pf2 = frag4(A0, B0, C0, D0);
            pf3 = frag4(A1, B1, C1, D1);
        }

        if (t < 31) {     // K(t+1) -> other buffer; overlaps PV (no barrier)
            *(bf16x8*)&Ks[nxt][SW64(kr, kc)] = nka;
            *(bf16x8*)&Ks[nxt][SW64(kr + 32, kc)] = nkb;
        }

        // ---- O^T += V^T · P^T  (A = VTs rows b128, B = P-frags in regs)
        #pragma unroll
        for (int js = 0; js < 4; js++) {
            bf16x8 av0 = *(const bf16x8*)&VTs[cur][SW64(l31, js * 16 + h8)];
            bf16x8 av1 = *(const bf16x8*)&VTs[cur][SW64(32 + l31, js * 16 + h8)];
            bf16x8 pb = (js == 0) ? pf0 : (js == 1) ? pf1 : (js == 2) ? pf2 : pf3;
            o_acc[0] = __builtin_amdgcn_mfma_f32_32x32x16_bf16(av0, pb, o_acc[0], 0, 0, 0);
            o_acc[1] = __builtin_amdgcn_mfma_f32_32x32x16_bf16(av1, pb, o_acc[1], 0, 0, 0);
        }

        if (t < 31) {     // V(t+1) transpose store -> other buffer
            #pragma unroll
            for (int j = 0; j < 8; j++)
                *(unsigned int*)&VTs[nxt][SW64(vc + j, vr2)] = pack2(nva[j], nvb[j]);
        }
    }

    // ---- epilogue: O^T lane holds q=l31, d = dt*32 + 8g + 4*hl + e
    float inv = 1.0f / l_i;
    const int orow = q0 + wave * 32 + l31;
    #pragma unroll
    for (int dt = 0; dt < 2; dt++)
        #pragma unroll
        for (int g = 0; g < 4; g++) {
            bf16x4 ov;
            #pragma unroll
            for (int e = 0; e < 4; e++) ov[e] = (__bf16)(o_acc[dt][g * 4 + e] * inv);
            *(bf16x4*)&Og[base + orow * 1024 + dt * 32 + g * 8 + hl * 4] = ov;
        }
}

// ---------------------------------------------------------------------------
extern "C" void kernel_launch(void* const* d_in, const int* in_sizes, int n_in,
                              void* d_out, int out_size, void* d_ws, size_t ws_size,
                              hipStream_t stream)
{
    int* flag = (int*)d_ws;
    __bf16* cv = (__bf16*)((char*)d_ws + 256);

    const int Z = 0, WQ = 8388608, WK = 8454144, WV = 8519680;
    const int FCQW = 8585216, FCKW = 8650752, FCVW = 8716288, FCOW = 8781824;
    const int FCQB = 9830400, FCKB = 9831424, FCVB = 9832448, FCOB = 9833472;
    __bf16* zb = cv + 10485760;
    __bf16* Qw = cv + 12582912;
    __bf16* Kw = Qw + 8388608;
    __bf16* Vw = Kw + 8388608;
    __bf16* Ow = cv + Z;  // reuse z-copy region (dead after proj1)

    detect_dtype<<<1, 256, 0, stream>>>((const unsigned short*)d_in[0], flag);

    ConvArgs ca;
    const int offs[12] = {Z, WQ, WK, WV, FCQW, FCQB, FCKW, FCKB, FCVW, FCVB, FCOW, FCOB};
    for (int i = 0; i < 12; i++) { ca.src[i] = d_in[i]; ca.n[i] = in_sizes[i]; ca.off[i] = offs[i]; }
    convert_inputs<<<dim3(4096, 1), 256, 0, stream>>>(ca, cv, flag, 0);
    convert_inputs<<<dim3(512, 11), 256, 0, stream>>>(ca, cv, flag, 1);

    gemm_bias<<<dim3(64, 1, 3), 256, 0, stream>>>(
        cv + Z, cv + Z, cv + Z, cv + WQ, cv + WK, cv + WV,
        cv + FCQB, cv + FCQB, cv + FCQB,
        zb, zb + 524288, zb + 1048576, 8192, 64, 1024, 0, nullptr,
        1.0f, 1.0f, 1.0f);

    const float QSC = 0.125f * 1.44269504088896f;  // fold 1/sqrt(dk) * log2(e) into Q
    gemm_bias<<<dim3(64, 16, 3), 256, 0, stream>>>(
        zb, zb + 524288, zb + 1048576,
        cv + FCQW, cv + FCKW, cv + FCVW, cv + FCQB, cv + FCKB, cv + FCVB,
        Qw, Kw, Vw, 8192, 1024, 64, 1, nullptr,
        QSC, 1.0f, 1.0f);

    attn_kernel<<<dim3(64, 16), 256, 0, stream>>>(Qw, Kw, Vw, Ow);

    gemm_bias<<<dim3(64, 16, 1), 256, 0, stream>>>(
        Ow, Ow, Ow, cv + FCOW, cv + FCOW, cv + FCOW, cv + FCOB, cv + FCOB, cv + FCOB,
        d_out, d_out, d_out, 8192, 1024, 1024, 1, flag,
        1.0f, 1.0f, 1.0f);
}

// Round 4
// 313.984 us; speedup vs baseline: 1.1249x; 1.0150x over previous
//
#include <hip/hip_runtime.h>

// multi_SelfAttention on MI355X (gfx950). Inputs fp32 (runtime-detected);
// bf16 MFMA compute; output dtype per flag.
// convert -> proj1 -> T(fc*_w) -> proj2 -> T(fco_w) -> flash attn -> proj3.
// r12: GEMM path rebuilt, attn byte-identical to r11 (106.4 us, for clean
// attribution). proj2/proj3 use gemm128: 128x128 tile, BK=64, 2x2 waves, BOTH
// operands DMA'd via global_load_lds width=16 with SW64-pre-swizzled global
// source addresses (linear LDS dest, swizzled read — m173 pattern), so staging
// costs zero VALU and zero bank conflicts. B is pre-transposed to [N,K] by
// transpose_w into dead regions (fc*_w^T -> wq/wk/wv region after proj1;
// fco_w^T -> zb region after proj2). proj1 (N=64) keeps the old kernel.

typedef __bf16 bf16x8 __attribute__((ext_vector_type(8)));
typedef __bf16 bf16x4 __attribute__((ext_vector_type(4)));
typedef __bf16 bf16x2 __attribute__((ext_vector_type(2)));
typedef float floatx4 __attribute__((ext_vector_type(4)));
typedef float floatx16 __attribute__((ext_vector_type(16)));
typedef unsigned int uintx4 __attribute__((ext_vector_type(4)));
typedef unsigned int uintx2 __attribute__((ext_vector_type(2)));

#define LDP 72  // padded stride for GEMM A tiles only (old kernel)

// 64-stride tile swizzle: 16B-chunk XOR; bank-uniform for row-major b128
// reads at fixed col, b128 row-staging writes, and b32 transpose stores.
#define SW64(row, col) (((row) << 6) | (((((col) >> 3) ^ ((row) & 7) ^ (((row) >> 3) & 7)) << 3) | ((col) & 7)))

#if __has_builtin(__builtin_amdgcn_exp2f)
__device__ __forceinline__ float fast_exp2(float x) { return __builtin_amdgcn_exp2f(x); }
#else
__device__ __forceinline__ float fast_exp2(float x) { return exp2f(x); }
#endif

__device__ __forceinline__ unsigned int pack_bf16(float lo, float hi) {
    bf16x2 w; w[0] = (__bf16)lo; w[1] = (__bf16)hi;
    return __builtin_bit_cast(unsigned int, w);
}
__device__ __forceinline__ unsigned int pack2(__bf16 lo, __bf16 hi) {
    bf16x2 w; w[0] = lo; w[1] = hi;
    return __builtin_bit_cast(unsigned int, w);
}
// Cross-half exchange (lanes 0-31 <-> 32-63), verified builtin w/ shfl fallback.
#if __has_builtin(__builtin_amdgcn_permlane32_swap)
__device__ __forceinline__ void xchg(unsigned int& X, unsigned int& Y, int) {
    uintx2 r = __builtin_amdgcn_permlane32_swap(X, Y, false, false);
    X = r[0]; Y = r[1];
}
#else
__device__ __forceinline__ void xchg(unsigned int& X, unsigned int& Y, int hl) {
    unsigned int sX = (unsigned int)__shfl_xor((int)X, 32);
    unsigned int sY = (unsigned int)__shfl_xor((int)Y, 32);
    unsigned int lo = hl ? sY : X;
    unsigned int hi = hl ? Y : sX;
    X = lo; Y = hi;
}
#endif
__device__ __forceinline__ bf16x8 frag4(unsigned int a, unsigned int b, unsigned int c, unsigned int d) {
    uintx4 u; u[0] = a; u[1] = b; u[2] = c; u[3] = d;
    return __builtin_bit_cast(bf16x8, u);
}
// Async global->LDS DMA, 16 B/lane. LDS base must be wave-uniform; HW writes
// base + lane*16. Global addr is per-lane (pre-swizzle it for swizzled layouts).
__device__ __forceinline__ void async_b128(const __bf16* g, __bf16* l) {
    __builtin_amdgcn_global_load_lds(
        (const __attribute__((address_space(1))) unsigned int*)g,
        (__attribute__((address_space(3))) unsigned int*)l, 16, 0, 0);
}

// ---------------------------------------------------------------------------
__global__ void detect_dtype(const unsigned short* __restrict__ z, int* __restrict__ flag) {
    __shared__ int cnt;
    if (threadIdx.x == 0) cnt = 0;
    __syncthreads();
    int local = 0;
    for (int i = threadIdx.x; i < 16384; i += 256) {
        unsigned int u = (unsigned int)z[i] << 16;
        float x = __uint_as_float(u);
        float ax = fabsf(x);
        if (!(ax <= 1024.0f) || (x != 0.0f && ax < 1e-20f)) local++;
    }
    atomicAdd(&cnt, local);
    __syncthreads();
    if (threadIdx.x == 0) *flag = (cnt > 1310) ? 1 : 0;
}

// ---------------------------------------------------------------------------
struct ConvArgs { const void* src[12]; int n[12]; int off[12]; };

__global__ void convert_inputs(ConvArgs a, __bf16* __restrict__ cv, const int* __restrict__ flag,
                               int base_k) {
    const int k = blockIdx.y + base_k;
    const int i = (blockIdx.x * 256 + threadIdx.x) * 8;
    if (i >= a.n[k]) return;
    __bf16* dst = cv + a.off[k] + i;
    if (*flag) {
        const float* s = (const float*)a.src[k] + i;
        float4 f0 = *(const float4*)s;
        float4 f1 = *(const float4*)(s + 4);
        bf16x8 v;
        v[0] = (__bf16)f0.x; v[1] = (__bf16)f0.y; v[2] = (__bf16)f0.z; v[3] = (__bf16)f0.w;
        v[4] = (__bf16)f1.x; v[5] = (__bf16)f1.y; v[6] = (__bf16)f1.z; v[7] = (__bf16)f1.w;
        *(bf16x8*)dst = v;
    } else {
        *(bf16x8*)dst = *(const bf16x8*)((const __bf16*)a.src[k] + i);
    }
}

// ---------------------------------------------------------------------------
// transpose_w: out[N=1024][K] = in[K][1024], 64x64 LDS tiles.
// grid (16, K/64, nz); z selects matrix via zstride.
// ---------------------------------------------------------------------------
__global__ __launch_bounds__(256) void transpose_w(
    const __bf16* __restrict__ in, __bf16* __restrict__ out, int K,
    int zsin, int zsout)
{
    in  += blockIdx.z * zsin;
    out += blockIdx.z * zsout;
    __shared__ __bf16 t[64][72];
    const int bn = blockIdx.x * 64, bk = blockIdx.y * 64;
    const int r = threadIdx.x >> 3, c8 = (threadIdx.x & 7) << 3;
    #pragma unroll
    for (int p = 0; p < 2; p++) {
        bf16x8 v = *(const bf16x8*)&in[(bk + p * 32 + r) * 1024 + bn + c8];
        #pragma unroll
        for (int j = 0; j < 8; j++) t[c8 + j][p * 32 + r] = v[j];
    }
    __syncthreads();
    #pragma unroll
    for (int p = 0; p < 2; p++) {
        bf16x8 v;
        #pragma unroll
        for (int j = 0; j < 8; j++) v[j] = t[p * 32 + r][c8 + j];
        *(bf16x8*)&out[(bn + p * 32 + r) * K + bk + c8] = v;
    }
}

// ---------------------------------------------------------------------------
// gemm_bias (legacy 128x64 tile) — used only for proj1 (N=64).
// ---------------------------------------------------------------------------
__global__ __launch_bounds__(256) void gemm_bias(
    const __bf16* __restrict__ A0, const __bf16* __restrict__ A1, const __bf16* __restrict__ A2,
    const __bf16* __restrict__ B0, const __bf16* __restrict__ B1, const __bf16* __restrict__ B2,
    const __bf16* __restrict__ bias0, const __bf16* __restrict__ bias1, const __bf16* __restrict__ bias2,
    void* __restrict__ C0, void* __restrict__ C1, void* __restrict__ C2,
    int M, int N, int K, int has_bias, const int* flagp,
    float os0, float os1, float os2)
{
    const int zsel = blockIdx.z;
    const __bf16* A = (zsel == 0) ? A0 : (zsel == 1) ? A1 : A2;
    const __bf16* B = (zsel == 0) ? B0 : (zsel == 1) ? B1 : B2;
    const __bf16* bias = (zsel == 0) ? bias0 : (zsel == 1) ? bias1 : bias2;
    void* C = (zsel == 0) ? C0 : (zsel == 1) ? C1 : C2;
    const float oscale = (zsel == 0) ? os0 : (zsel == 1) ? os1 : os2;
    const int out_fp32 = flagp ? *flagp : 0;

    const int m0 = blockIdx.x * 128;
    const int n0 = blockIdx.y * 64;
    const int tid = threadIdx.x;
    const int wave = tid >> 6;
    const int ln = tid & 15;
    const int quad = (tid >> 4) & 3;

    __shared__ __bf16 As[128 * LDP];
    __shared__ __bf16 Bts[64 * 64];   // SW64-swizzled [n][k]

    floatx4 acc[2][4] = {};

    for (int k0 = 0; k0 < K; k0 += 64) {
        __syncthreads();
        for (int i = tid; i < 1024; i += 256) {
            int r = i >> 3, c8 = (i & 7) << 3;
            *(bf16x8*)&As[r * LDP + c8] = *(const bf16x8*)&A[(m0 + r) * K + k0 + c8];
        }
        for (int i = tid; i < 512; i += 256) {
            int kk = i >> 3, a8 = (i & 7) << 3;
            bf16x8 v = *(const bf16x8*)&B[(k0 + kk) * N + n0 + a8];
            #pragma unroll
            for (int j = 0; j < 8; j++) Bts[SW64(a8 + j, kk)] = v[j];
        }
        __syncthreads();
        #pragma unroll
        for (int ks = 0; ks < 2; ks++) {
            bf16x8 a[2], b[4];
            a[0] = *(const bf16x8*)&As[(wave * 32 + ln) * LDP + ks * 32 + quad * 8];
            a[1] = *(const bf16x8*)&As[(wave * 32 + 16 + ln) * LDP + ks * 32 + quad * 8];
            #pragma unroll
            for (int nt = 0; nt < 4; nt++)
                b[nt] = *(const bf16x8*)&Bts[SW64(nt * 16 + ln, ks * 32 + quad * 8)];
            #pragma unroll
            for (int rt = 0; rt < 2; rt++)
                #pragma unroll
                for (int nt = 0; nt < 4; nt++)
                    acc[rt][nt] = __builtin_amdgcn_mfma_f32_16x16x32_bf16(a[rt], b[nt], acc[rt][nt], 0, 0, 0);
        }
    }
    #pragma unroll
    for (int rt = 0; rt < 2; rt++) {
        const int row = m0 + wave * 32 + rt * 16 + quad * 4;
        #pragma unroll
        for (int nt = 0; nt < 4; nt++) {
            const int col = n0 + nt * 16 + ln;
            float bv = has_bias ? (float)bias[col] : 0.0f;
            #pragma unroll
            for (int r = 0; r < 4; r++) {
                float val = (acc[rt][nt][r] + bv) * oscale;
                if (out_fp32) ((float*)C)[(row + r) * N + col] = val;
                else ((__bf16*)C)[(row + r) * N + col] = (__bf16)val;
            }
        }
    }
}

// ---------------------------------------------------------------------------
// gemm128: C[M,N] = (A @ BT^T + bias) * os. A[M,K], BT[N,K] both row-major.
// 128x128 tile, BK=64, 2x2 waves (64x64 out each). Both tiles staged with
// global_load_lds w=16: linear LDS dest, SW64-pre-swizzled global source, so
// the SW64 b128 fragment reads below are conflict-free with ZERO staging VALU.
// ---------------------------------------------------------------------------
__global__ __launch_bounds__(256, 2) void gemm128(
    const __bf16* __restrict__ A0, const __bf16* __restrict__ A1, const __bf16* __restrict__ A2,
    const __bf16* __restrict__ BT0, const __bf16* __restrict__ BT1, const __bf16* __restrict__ BT2,
    const __bf16* __restrict__ bias0, const __bf16* __restrict__ bias1, const __bf16* __restrict__ bias2,
    void* __restrict__ C0, void* __restrict__ C1, void* __restrict__ C2,
    int M, int N, int K, const int* flagp,
    float os0, float os1, float os2)
{
    const int zsel = blockIdx.z;
    const __bf16* A = (zsel == 0) ? A0 : (zsel == 1) ? A1 : A2;
    const __bf16* BT = (zsel == 0) ? BT0 : (zsel == 1) ? BT1 : BT2;
    const __bf16* bias = (zsel == 0) ? bias0 : (zsel == 1) ? bias1 : bias2;
    void* C = (zsel == 0) ? C0 : (zsel == 1) ? C1 : C2;
    const float oscale = (zsel == 0) ? os0 : (zsel == 1) ? os1 : os2;
    const int out_fp32 = flagp ? *flagp : 0;

    const int m0 = blockIdx.x * 128;
    const int n0 = blockIdx.y * 128;
    const int tid = threadIdx.x;
    const int wave = tid >> 6, ln = tid & 63;
    const int wr = wave >> 1, wc = wave & 1;    // 2x2 wave grid
    const int l15 = tid & 15, quad = (tid >> 4) & 3;

    __shared__ __bf16 As[128 * 64];   // SW64 layout [m][k], 16 KB
    __shared__ __bf16 Bs[128 * 64];   // SW64 layout [n][k], 16 KB

    // DMA lane map: seg = wave*4+it covers rows seg*8..+7 (1024 B); lane ->
    // (row = seg*8 + ln>>3, chunk j = ln&7); source chunk = j ^ SW64-xor(row)
    // so the linear DMA write yields the SW64 layout.
    const int r_off = ln >> 3, j_off = ln & 7;

    floatx4 acc[4][4] = {};

    for (int k0 = 0; k0 < K; k0 += 64) {
        __syncthreads();
        #pragma unroll
        for (int it = 0; it < 4; it++) {
            const int seg = wave * 4 + it;
            const int row = seg * 8 + r_off;
            const int c = j_off ^ (row & 7) ^ ((row >> 3) & 7);
            async_b128(&A[(m0 + row) * K + k0 + c * 8], &As[seg * 512]);
            async_b128(&BT[(n0 + row) * K + k0 + c * 8], &Bs[seg * 512]);
        }
        __syncthreads();
        #pragma unroll
        for (int ks = 0; ks < 2; ks++) {
            bf16x8 a[4], b[4];
            #pragma unroll
            for (int rt = 0; rt < 4; rt++)
                a[rt] = *(const bf16x8*)&As[SW64(wr * 64 + rt * 16 + l15, ks * 32 + quad * 8)];
            #pragma unroll
            for (int nt = 0; nt < 4; nt++)
                b[nt] = *(const bf16x8*)&Bs[SW64(wc * 64 + nt * 16 + l15, ks * 32 + quad * 8)];
            #pragma unroll
            for (int rt = 0; rt < 4; rt++)
                #pragma unroll
                for (int nt = 0; nt < 4; nt++)
                    acc[rt][nt] = __builtin_amdgcn_mfma_f32_16x16x32_bf16(a[rt], b[nt], acc[rt][nt], 0, 0, 0);
        }
    }
    #pragma unroll
    for (int rt = 0; rt < 4; rt++) {
        const int row = m0 + wr * 64 + rt * 16 + quad * 4;
        #pragma unroll
        for (int nt = 0; nt < 4; nt++) {
            const int col = n0 + wc * 64 + nt * 16 + l15;
            float bv = (float)bias[col];
            #pragma unroll
            for (int r = 0; r < 4; r++) {
                float val = (acc[rt][nt][r] + bv) * oscale;
                if (out_fp32) ((float*)C)[(row + r) * N + col] = val;
                else ((__bf16*)C)[(row + r) * N + col] = (__bf16)val;
            }
        }
    }
}

// ---------------------------------------------------------------------------
// Flash attention r11 (32x32 S^T / O^T, in-register P, single-barrier loop).
// BYTE-IDENTICAL to r11 (106.4 us) for clean attribution of the GEMM changes.
// ---------------------------------------------------------------------------
__global__ __launch_bounds__(256, 3) void attn_kernel(
    const __bf16* __restrict__ Qg, const __bf16* __restrict__ Kg,
    const __bf16* __restrict__ Vg, __bf16* __restrict__ Og)
{
    const int bh = blockIdx.x;
    const int b = bh >> 4, h = bh & 15;
    const int q0 = blockIdx.y * 128;
    const int base = b * 2048 * 1024 + h * 64;
    const int tid = threadIdx.x;
    const int wave = tid >> 6, ln = tid & 63;
    const int l31 = ln & 31, hl = ln >> 5;    // lane-in-32, lane half
    const int h8 = hl * 8;

    __shared__ __bf16 Ks[2][64 * 64];     // 16 KB, double buffer, SW64 [j][k]
    __shared__ __bf16 VTs[2][64 * 64];    // 16 KB, double buffer, SW64 [d][j]

    // Q fragments (B-operand of S^T): lane n=q=l31, k = ks*16 + h8 + e
    bf16x8 qf[4];
    #pragma unroll
    for (int ks = 0; ks < 4; ks++)
        qf[ks] = *(const bf16x8*)&Qg[base + (q0 + wave * 32 + l31) * 1024 + ks * 16 + h8];

    const int kr = tid >> 3, kc = (tid & 7) << 3;   // K staging: rows kr, kr+32
    const int vr2 = (tid >> 3) * 2, vc = (tid & 7) << 3;  // V staging: row pair

    {   // tile 0 (published by the t=0 barrier)
        bf16x8 ka = *(const bf16x8*)&Kg[base + kr * 1024 + kc];
        bf16x8 kb = *(const bf16x8*)&Kg[base + (kr + 32) * 1024 + kc];
        bf16x8 va = *(const bf16x8*)&Vg[base + vr2 * 1024 + vc];
        bf16x8 vb = *(const bf16x8*)&Vg[base + (vr2 + 1) * 1024 + vc];
        *(bf16x8*)&Ks[0][SW64(kr, kc)] = ka;
        *(bf16x8*)&Ks[0][SW64(kr + 32, kc)] = kb;
        #pragma unroll
        for (int j = 0; j < 8; j++)
            *(unsigned int*)&VTs[0][SW64(vc + j, vr2)] = pack2(va[j], vb[j]);
    }

    floatx16 o_acc[2] = {};
    float m_i = -1e30f, l_i = 0.0f;

    for (int t = 0; t < 32; t++) {
        const int cur = t & 1, nxt = cur ^ 1;
        bf16x8 nka, nkb, nva, nvb;          // K/V(t+1) register prefetch
        if (t < 31) {
            const int kvn = (t + 1) * 64;
            nka = *(const bf16x8*)&Kg[base + (kvn + kr) * 1024 + kc];
            nkb = *(const bf16x8*)&Kg[base + (kvn + kr + 32) * 1024 + kc];
            nva = *(const bf16x8*)&Vg[base + (kvn + vr2) * 1024 + vc];
            nvb = *(const bf16x8*)&Vg[base + (kvn + vr2 + 1) * 1024 + vc];
        }
        __syncthreads();  // writes(t-1) -> nxt_{t-1}=cur visible; reads(t-1) drained

        // ---- S^T = K · Q^T: lane q=l31; j = (r&3)+8*(r>>2)+4*hl (+32 for s1)
        floatx16 sv[2] = {};
        #pragma unroll
        for (int ks = 0; ks < 4; ks++) {
            bf16x8 a0 = *(const bf16x8*)&Ks[cur][SW64(l31, ks * 16 + h8)];
            bf16x8 a1 = *(const bf16x8*)&Ks[cur][SW64(32 + l31, ks * 16 + h8)];
            sv[0] = __builtin_amdgcn_mfma_f32_32x32x16_bf16(a0, qf[ks], sv[0], 0, 0, 0);
            sv[1] = __builtin_amdgcn_mfma_f32_32x32x16_bf16(a1, qf[ks], sv[1], 0, 0, 0);
        }

        // ---- softmax for q=l31 over 64 j: own-32 tree + partner half
        float m8[8];
        #pragma unroll
        for (int r = 0; r < 8; r++)
            m8[r] = fmaxf(fmaxf(sv[0][r], sv[0][r + 8]), fmaxf(sv[1][r], sv[1][r + 8]));
        float mx = fmaxf(fmaxf(fmaxf(m8[0], m8[4]), fmaxf(m8[1], m8[5])),
                         fmaxf(fmaxf(m8[2], m8[6]), fmaxf(m8[3], m8[7])));
        mx = fmaxf(mx, __shfl_xor(mx, 32));

        if (__any(mx > m_i + 8.0f)) {       // defer-max: rescale only on big jumps
            float m_new = fmaxf(m_i, mx);
            float alpha = fast_exp2(m_i - m_new);
            m_i = m_new;
            l_i *= alpha;
            #pragma unroll
            for (int dt = 0; dt < 2; dt++)
                #pragma unroll
                for (int r = 0; r < 16; r++) o_acc[dt][r] *= alpha;
        }

        float p0[16], p1[16];
        #pragma unroll
        for (int r = 0; r < 16; r++) p0[r] = fast_exp2(sv[0][r] - m_i);
        #pragma unroll
        for (int r = 0; r < 16; r++) p1[r] = fast_exp2(sv[1][r] - m_i);
        float rsA = 0.f, rsB = 0.f, rsC = 0.f, rsD = 0.f;
        #pragma unroll
        for (int r = 0; r < 16; r += 4) {
            rsA += p0[r]; rsB += p0[r + 1]; rsC += p0[r + 2]; rsD += p0[r + 3];
            rsA += p1[r]; rsB += p1[r + 1]; rsC += p1[r + 2]; rsD += p1[r + 3];
        }
        float rs = (rsA + rsB) + (rsC + rsD);
        rs += __shfl_xor(rs, 32);
        l_i += rs;

        // ---- P -> bf16 B-frags in registers (pack pairs; cross-half exchange)
        bf16x8 pf0, pf1, pf2, pf3;
        {
            unsigned int A0 = pack_bf16(p0[0], p0[1]),  B0 = pack_bf16(p0[2], p0[3]);
            unsigned int C0 = pack_bf16(p0[4], p0[5]),  D0 = pack_bf16(p0[6], p0[7]);
            unsigned int A1 = pack_bf16(p0[8], p0[9]),  B1 = pack_bf16(p0[10], p0[11]);
            unsigned int C1 = pack_bf16(p0[12], p0[13]), D1 = pack_bf16(p0[14], p0[15]);
            xchg(A0, C0, hl); xchg(B0, D0, hl); xchg(A1, C1, hl); xchg(B1, D1, hl);
            pf0 = frag4(A0, B0, C0, D0);
            pf1 = frag4(A1, B1, C1, D1);
        }
        {
            unsigned int A0 = pack_bf16(p1[0], p1[1]),  B0 = pack_bf16(p1[2], p1[3]);
            unsigned int C0 = pack_bf16(p1[4], p1[5]),  D0 = pack_bf16(p1[6], p1[7]);
            unsigned int A1 = pack_bf16(p1[8], p1[9]),  B1 = pack_bf16(p1[10], p1[11]);
            unsigned int C1 = pack_bf16(p1[12], p1[13]), D1 = pack_bf16(p1[14], p1[15]);
            xchg(A0, C0, hl); xchg(B0, D0, hl); xchg(A1, C1, hl); xchg(B1, D1, hl);
            pf2 = frag4(A0, B0, C0, D0);
            pf3 = frag4(A1, B1, C1, D1);
        }

        if (t < 31) {     // K(t+1) -> other buffer; overlaps PV (no barrier)
            *(bf16x8*)&Ks[nxt][SW64(kr, kc)] = nka;
            *(bf16x8*)&Ks[nxt][SW64(kr + 32, kc)] = nkb;
        }

        // ---- O^T += V^T · P^T  (A = VTs rows b128, B = P-frags in regs)
        #pragma unroll
        for (int js = 0; js < 4; js++) {
            bf16x8 av0 = *(const bf16x8*)&VTs[cur][SW64(l31, js * 16 + h8)];
            bf16x8 av1 = *(const bf16x8*)&VTs[cur][SW64(32 + l31, js * 16 + h8)];
            bf16x8 pb = (js == 0) ? pf0 : (js == 1) ? pf1 : (js == 2) ? pf2 : pf3;
            o_acc[0] = __builtin_amdgcn_mfma_f32_32x32x16_bf16(av0, pb, o_acc[0], 0, 0, 0);
            o_acc[1] = __builtin_amdgcn_mfma_f32_32x32x16_bf16(av1, pb, o_acc[1], 0, 0, 0);
        }

        if (t < 31) {     // V(t+1) transpose store -> other buffer
            #pragma unroll
            for (int j = 0; j < 8; j++)
                *(unsigned int*)&VTs[nxt][SW64(vc + j, vr2)] = pack2(nva[j], nvb[j]);
        }
    }

    // ---- epilogue: O^T lane holds q=l31, d = dt*32 + 8g + 4*hl + e
    float inv = 1.0f / l_i;
    const int orow = q0 + wave * 32 + l31;
    #pragma unroll
    for (int dt = 0; dt < 2; dt++)
        #pragma unroll
        for (int g = 0; g < 4; g++) {
            bf16x4 ov;
            #pragma unroll
            for (int e = 0; e < 4; e++) ov[e] = (__bf16)(o_acc[dt][g * 4 + e] * inv);
            *(bf16x4*)&Og[base + orow * 1024 + dt * 32 + g * 8 + hl * 4] = ov;
        }
}

// ---------------------------------------------------------------------------
extern "C" void kernel_launch(void* const* d_in, const int* in_sizes, int n_in,
                              void* d_out, int out_size, void* d_ws, size_t ws_size,
                              hipStream_t stream)
{
    int* flag = (int*)d_ws;
    __bf16* cv = (__bf16*)((char*)d_ws + 256);

    const int Z = 0, WQ = 8388608, WK = 8454144, WV = 8519680;
    const int FCQW = 8585216, FCKW = 8650752, FCVW = 8716288, FCOW = 8781824;
    const int FCQB = 9830400, FCKB = 9831424, FCVB = 9832448, FCOB = 9833472;
    __bf16* zb = cv + 10485760;
    __bf16* Qw = cv + 12582912;
    __bf16* Kw = Qw + 8388608;
    __bf16* Vw = Kw + 8388608;
    __bf16* Ow = cv + Z;        // reuse z-copy region (dead after proj1)
    __bf16* WT3 = cv + WQ;      // fc{q,k,v}_w^T [1024,64]x3 — wq region, dead after proj1
    __bf16* OWT = zb;           // fco_w^T [1024,1024] — zb region, dead after proj2

    detect_dtype<<<1, 256, 0, stream>>>((const unsigned short*)d_in[0], flag);

    ConvArgs ca;
    const int offs[12] = {Z, WQ, WK, WV, FCQW, FCQB, FCKW, FCKB, FCVW, FCVB, FCOW, FCOB};
    for (int i = 0; i < 12; i++) { ca.src[i] = d_in[i]; ca.n[i] = in_sizes[i]; ca.off[i] = offs[i]; }
    convert_inputs<<<dim3(4096, 1), 256, 0, stream>>>(ca, cv, flag, 0);
    convert_inputs<<<dim3(512, 11), 256, 0, stream>>>(ca, cv, flag, 1);

    // proj1: zb[8192,64]x3 = z @ w{q,k,v}
    gemm_bias<<<dim3(64, 1, 3), 256, 0, stream>>>(
        cv + Z, cv + Z, cv + Z, cv + WQ, cv + WK, cv + WV,
        cv + FCQB, cv + FCQB, cv + FCQB,
        zb, zb + 524288, zb + 1048576, 8192, 64, 1024, 0, nullptr,
        1.0f, 1.0f, 1.0f);

    // fc{q,k,v}_w [64,1024] -> ^T [1024,64] into dead wq/wk/wv region
    transpose_w<<<dim3(16, 1, 3), 256, 0, stream>>>(cv + FCQW, WT3, 64, 65536, 65536);

    const float QSC = 0.125f * 1.44269504088896f;  // fold 1/sqrt(dk) * log2(e) into Q
    // proj2: Q/K/V[8192,1024] = zb @ fc*_w + b
    gemm128<<<dim3(64, 8, 3), 256, 0, stream>>>(
        zb, zb + 524288, zb + 1048576,
        WT3, WT3 + 65536, WT3 + 131072,
        cv + FCQB, cv + FCKB, cv + FCVB,
        Qw, Kw, Vw, 8192, 1024, 64, nullptr,
        QSC, 1.0f, 1.0f);

    // fco_w [1024,1024] -> ^T into dead zb region
    transpose_w<<<dim3(16, 16, 1), 256, 0, stream>>>(cv + FCOW, OWT, 1024, 0, 0);

    attn_kernel<<<dim3(64, 16), 256, 0, stream>>>(Qw, Kw, Vw, Ow);

    // proj3: out[8192,1024] = Ow @ fco_w + b
    gemm128<<<dim3(64, 8, 1), 256, 0, stream>>>(
        Ow, Ow, Ow, OWT, OWT, OWT,
        cv + FCOB, cv + FCOB, cv + FCOB,
        d_out, d_out, d_out, 8192, 1024, 1024, flag,
        1.0f, 1.0f, 1.0f);
}

// Round 6
// 267.504 us; speedup vs baseline: 1.3204x; 1.1738x over previous
//
#include <hip/hip_runtime.h>

// multi_SelfAttention on MI355X (gfx950). Inputs fp32 (runtime-detected);
// bf16 MFMA compute; output dtype per flag.
// r13 (resubmit; previous round was an infra container failure, no data):
// pipeline collapsed 9 -> 6 launches. mega_convert does z + biases +
// transpose-convert of ALL 7 weight matrices straight from the fp32 source
// (wq/wk/wv -> ^T for proj1 BT; fc*_w -> ^T for proj2 BT; fco_w -> ^T for
// proj3 BT), killing the separate transpose kernels and their round trips.
// proj1 rebuilt as gemm64 (64x64 tile, global_load_lds staging both operands,
// 384 blocks). proj2/proj3 = gemm128 (unchanged). attn = r11 byte-identical
// (106-112 us; run-to-run variance ~±5 us).
// Launches: detect -> mega_convert -> gemm64 -> gemm128(proj2) -> attn ->
// gemm128(proj3).

typedef __bf16 bf16x8 __attribute__((ext_vector_type(8)));
typedef __bf16 bf16x4 __attribute__((ext_vector_type(4)));
typedef __bf16 bf16x2 __attribute__((ext_vector_type(2)));
typedef float floatx4 __attribute__((ext_vector_type(4)));
typedef float floatx16 __attribute__((ext_vector_type(16)));
typedef unsigned int uintx4 __attribute__((ext_vector_type(4)));
typedef unsigned int uintx2 __attribute__((ext_vector_type(2)));

// 64-stride tile swizzle: 16B-chunk XOR; bank-uniform for row-major b128
// reads at fixed col, b128 row-staging writes, and b32 transpose stores.
#define SW64(row, col) (((row) << 6) | (((((col) >> 3) ^ ((row) & 7) ^ (((row) >> 3) & 7)) << 3) | ((col) & 7)))

#if __has_builtin(__builtin_amdgcn_exp2f)
__device__ __forceinline__ float fast_exp2(float x) { return __builtin_amdgcn_exp2f(x); }
#else
__device__ __forceinline__ float fast_exp2(float x) { return exp2f(x); }
#endif

__device__ __forceinline__ unsigned int pack_bf16(float lo, float hi) {
    bf16x2 w; w[0] = (__bf16)lo; w[1] = (__bf16)hi;
    return __builtin_bit_cast(unsigned int, w);
}
__device__ __forceinline__ unsigned int pack2(__bf16 lo, __bf16 hi) {
    bf16x2 w; w[0] = lo; w[1] = hi;
    return __builtin_bit_cast(unsigned int, w);
}
// Cross-half exchange (lanes 0-31 <-> 32-63), verified builtin w/ shfl fallback.
#if __has_builtin(__builtin_amdgcn_permlane32_swap)
__device__ __forceinline__ void xchg(unsigned int& X, unsigned int& Y, int) {
    uintx2 r = __builtin_amdgcn_permlane32_swap(X, Y, false, false);
    X = r[0]; Y = r[1];
}
#else
__device__ __forceinline__ void xchg(unsigned int& X, unsigned int& Y, int hl) {
    unsigned int sX = (unsigned int)__shfl_xor((int)X, 32);
    unsigned int sY = (unsigned int)__shfl_xor((int)Y, 32);
    unsigned int lo = hl ? sY : X;
    unsigned int hi = hl ? Y : sX;
    X = lo; Y = hi;
}
#endif
__device__ __forceinline__ bf16x8 frag4(unsigned int a, unsigned int b, unsigned int c, unsigned int d) {
    uintx4 u; u[0] = a; u[1] = b; u[2] = c; u[3] = d;
    return __builtin_bit_cast(bf16x8, u);
}
// Async global->LDS DMA, 16 B/lane. LDS base must be wave-uniform; HW writes
// base + lane*16. Global addr is per-lane (pre-swizzle it for swizzled layouts).
__device__ __forceinline__ void async_b128(const __bf16* g, __bf16* l) {
    __builtin_amdgcn_global_load_lds(
        (const __attribute__((address_space(1))) unsigned int*)g,
        (__attribute__((address_space(3))) unsigned int*)l, 16, 0, 0);
}

__device__ __forceinline__ bf16x8 cvt8(const void* src, int f, long idx) {
    bf16x8 v;
    if (f) {
        const float* s = (const float*)src + idx;
        float4 f0 = *(const float4*)s;
        float4 f1 = *(const float4*)(s + 4);
        v[0] = (__bf16)f0.x; v[1] = (__bf16)f0.y; v[2] = (__bf16)f0.z; v[3] = (__bf16)f0.w;
        v[4] = (__bf16)f1.x; v[5] = (__bf16)f1.y; v[6] = (__bf16)f1.z; v[7] = (__bf16)f1.w;
    } else {
        v = *(const bf16x8*)((const __bf16*)src + idx);
    }
    return v;
}

// ---------------------------------------------------------------------------
__global__ void detect_dtype(const unsigned short* __restrict__ z, int* __restrict__ flag) {
    __shared__ int cnt;
    if (threadIdx.x == 0) cnt = 0;
    __syncthreads();
    int local = 0;
    for (int i = threadIdx.x; i < 16384; i += 256) {
        unsigned int u = (unsigned int)z[i] << 16;
        float x = __uint_as_float(u);
        float ax = fabsf(x);
        if (!(ax <= 1024.0f) || (x != 0.0f && ax < 1e-20f)) local++;
    }
    atomicAdd(&cnt, local);
    __syncthreads();
    if (threadIdx.x == 0) *flag = (cnt > 1310) ? 1 : 0;
}

// ---------------------------------------------------------------------------
// mega_convert: one kernel for the whole input-prep stage.
//   blocks [0,4096):   z [8192,1024] convert/copy -> cv+0
//   blocks [4096,4098): 4 biases (consecutive dst at cv+9830400)
//   blocks [4098,4450): 64x64 transpose-convert tiles for 7 weight matrices:
//     t<48:  wq/wk/wv [1024,64] -> ^T [64,1024]   at cv+8388608 + m*65536
//     t<96:  fc*_w    [64,1024] -> ^T [1024,64]   at cv+8585216 + m*65536
//     else:  fco_w  [1024,1024] -> ^T [1024,1024] at cv+8781824
// ---------------------------------------------------------------------------
struct MegaArgs { const void* z; const void* bias[4]; const void* w[7]; };

__global__ __launch_bounds__(256) void mega_convert(MegaArgs a, __bf16* __restrict__ cv,
                                                    const int* __restrict__ flag) {
    const int f = *flag;
    const unsigned int blk = blockIdx.x;
    const int tid = threadIdx.x;

    if (blk < 4096) {           // z: 8388608 elems
        const long i = ((long)blk * 256 + tid) * 8;
        *(bf16x8*)&cv[i] = cvt8(a.z, f, i);
        return;
    }
    if (blk < 4098) {           // biases: 4 x 1024, consecutive dst
        const int idx = (((int)blk - 4096) * 256 + tid) * 8;
        const int b = idx >> 10, o = idx & 1023;
        *(bf16x8*)&cv[9830400 + b * 1024 + o] = cvt8(a.bias[b], f, o);
        return;
    }
    // ---- transpose-convert tiles
    const int t = blk - 4098;
    int bx, by, R, C;
    const void* src;
    __bf16* dst;
    if (t < 48) {
        const int m = t >> 4; by = t & 15; bx = 0; R = 1024; C = 64;
        src = a.w[m]; dst = cv + 8388608 + m * 65536;
    } else if (t < 96) {
        const int m = (t - 48) >> 4; bx = (t - 48) & 15; by = 0; R = 64; C = 1024;
        src = a.w[3 + m]; dst = cv + 8585216 + m * 65536;
    } else {
        const int u = t - 96; bx = u & 15; by = u >> 4; R = 1024; C = 1024;
        src = a.w[6]; dst = cv + 8781824;
    }
    __shared__ __bf16 tl[64][72];
    const int r0 = by * 64, c0 = bx * 64;
    const int rr = tid >> 3, c8 = (tid & 7) << 3;
    #pragma unroll
    for (int p = 0; p < 2; p++) {
        bf16x8 v = cvt8(src, f, (long)(r0 + p * 32 + rr) * C + c0 + c8);
        #pragma unroll
        for (int j = 0; j < 8; j++) tl[c8 + j][p * 32 + rr] = v[j];
    }
    __syncthreads();
    #pragma unroll
    for (int p = 0; p < 2; p++) {
        bf16x8 v;
        #pragma unroll
        for (int j = 0; j < 8; j++) v[j] = tl[p * 32 + rr][c8 + j];
        *(bf16x8*)&dst[(long)(c0 + p * 32 + rr) * R + r0 + c8] = v;
    }
}

// ---------------------------------------------------------------------------
// gemm64 (proj1): C[M,64] = A[M,K] @ BT[64,K]^T, bf16, no bias.
// 64x64 tile, BK=64, 4 waves (16 rows each). Both operands via global_load_lds
// with SW64-pre-swizzled source addresses (zero staging VALU, conflict-free).
// ---------------------------------------------------------------------------
__global__ __launch_bounds__(256, 2) void gemm64(
    const __bf16* __restrict__ A,
    const __bf16* __restrict__ BT0, const __bf16* __restrict__ BT1, const __bf16* __restrict__ BT2,
    __bf16* __restrict__ C0, __bf16* __restrict__ C1, __bf16* __restrict__ C2,
    int K)
{
    const int zsel = blockIdx.z;
    const __bf16* BT = (zsel == 0) ? BT0 : (zsel == 1) ? BT1 : BT2;
    __bf16* C = (zsel == 0) ? C0 : (zsel == 1) ? C1 : C2;
    const int m0 = blockIdx.x * 64;
    const int tid = threadIdx.x;
    const int wave = tid >> 6, ln = tid & 63;
    const int l15 = tid & 15, quad = (tid >> 4) & 3;

    __shared__ __bf16 As[64 * 64];   // SW64 [m][k], 8 KB
    __shared__ __bf16 Bs[64 * 64];   // SW64 [n][k], 8 KB

    const int r_off = ln >> 3, j_off = ln & 7;
    floatx4 acc[4] = {};

    for (int k0 = 0; k0 < K; k0 += 64) {
        __syncthreads();
        #pragma unroll
        for (int it = 0; it < 2; it++) {
            const int seg = wave * 2 + it;
            const int row = seg * 8 + r_off;
            const int c = j_off ^ (row & 7) ^ ((row >> 3) & 7);
            async_b128(&A[(long)(m0 + row) * K + k0 + c * 8], &As[seg * 512]);
            async_b128(&BT[(long)row * K + k0 + c * 8], &Bs[seg * 512]);
        }
        __syncthreads();
        #pragma unroll
        for (int ks = 0; ks < 2; ks++) {
            bf16x8 av = *(const bf16x8*)&As[SW64(wave * 16 + l15, ks * 32 + quad * 8)];
            #pragma unroll
            for (int nt = 0; nt < 4; nt++) {
                bf16x8 bv = *(const bf16x8*)&Bs[SW64(nt * 16 + l15, ks * 32 + quad * 8)];
                acc[nt] = __builtin_amdgcn_mfma_f32_16x16x32_bf16(av, bv, acc[nt], 0, 0, 0);
            }
        }
    }
    #pragma unroll
    for (int nt = 0; nt < 4; nt++) {
        const int col = nt * 16 + l15;
        #pragma unroll
        for (int r = 0; r < 4; r++)
            C[(long)(m0 + wave * 16 + quad * 4 + r) * 64 + col] = (__bf16)acc[nt][r];
    }
}

// ---------------------------------------------------------------------------
// gemm128: C[M,N] = (A @ BT^T + bias) * os. A[M,K], BT[N,K] both row-major.
// 128x128 tile, BK=64, 2x2 waves. Both tiles via global_load_lds w=16 with
// SW64-pre-swizzled source (zero staging VALU, conflict-free frag reads).
// ---------------------------------------------------------------------------
__global__ __launch_bounds__(256, 2) void gemm128(
    const __bf16* __restrict__ A0, const __bf16* __restrict__ A1, const __bf16* __restrict__ A2,
    const __bf16* __restrict__ BT0, const __bf16* __restrict__ BT1, const __bf16* __restrict__ BT2,
    const __bf16* __restrict__ bias0, const __bf16* __restrict__ bias1, const __bf16* __restrict__ bias2,
    void* __restrict__ C0, void* __restrict__ C1, void* __restrict__ C2,
    int M, int N, int K, const int* flagp,
    float os0, float os1, float os2)
{
    const int zsel = blockIdx.z;
    const __bf16* A = (zsel == 0) ? A0 : (zsel == 1) ? A1 : A2;
    const __bf16* BT = (zsel == 0) ? BT0 : (zsel == 1) ? BT1 : BT2;
    const __bf16* bias = (zsel == 0) ? bias0 : (zsel == 1) ? bias1 : bias2;
    void* C = (zsel == 0) ? C0 : (zsel == 1) ? C1 : C2;
    const float oscale = (zsel == 0) ? os0 : (zsel == 1) ? os1 : os2;
    const int out_fp32 = flagp ? *flagp : 0;

    const int m0 = blockIdx.x * 128;
    const int n0 = blockIdx.y * 128;
    const int tid = threadIdx.x;
    const int wave = tid >> 6, ln = tid & 63;
    const int wr = wave >> 1, wc = wave & 1;    // 2x2 wave grid
    const int l15 = tid & 15, quad = (tid >> 4) & 3;

    __shared__ __bf16 As[128 * 64];   // SW64 layout [m][k], 16 KB
    __shared__ __bf16 Bs[128 * 64];   // SW64 layout [n][k], 16 KB

    const int r_off = ln >> 3, j_off = ln & 7;

    floatx4 acc[4][4] = {};

    for (int k0 = 0; k0 < K; k0 += 64) {
        __syncthreads();
        #pragma unroll
        for (int it = 0; it < 4; it++) {
            const int seg = wave * 4 + it;
            const int row = seg * 8 + r_off;
            const int c = j_off ^ (row & 7) ^ ((row >> 3) & 7);
            async_b128(&A[(long)(m0 + row) * K + k0 + c * 8], &As[seg * 512]);
            async_b128(&BT[(long)(n0 + row) * K + k0 + c * 8], &Bs[seg * 512]);
        }
        __syncthreads();
        #pragma unroll
        for (int ks = 0; ks < 2; ks++) {
            bf16x8 a[4], b[4];
            #pragma unroll
            for (int rt = 0; rt < 4; rt++)
                a[rt] = *(const bf16x8*)&As[SW64(wr * 64 + rt * 16 + l15, ks * 32 + quad * 8)];
            #pragma unroll
            for (int nt = 0; nt < 4; nt++)
                b[nt] = *(const bf16x8*)&Bs[SW64(wc * 64 + nt * 16 + l15, ks * 32 + quad * 8)];
            #pragma unroll
            for (int rt = 0; rt < 4; rt++)
                #pragma unroll
                for (int nt = 0; nt < 4; nt++)
                    acc[rt][nt] = __builtin_amdgcn_mfma_f32_16x16x32_bf16(a[rt], b[nt], acc[rt][nt], 0, 0, 0);
        }
    }
    #pragma unroll
    for (int rt = 0; rt < 4; rt++) {
        const int row = m0 + wr * 64 + rt * 16 + quad * 4;
        #pragma unroll
        for (int nt = 0; nt < 4; nt++) {
            const int col = n0 + wc * 64 + nt * 16 + l15;
            float bv = (float)bias[col];
            #pragma unroll
            for (int r = 0; r < 4; r++) {
                float val = (acc[rt][nt][r] + bv) * oscale;
                if (out_fp32) ((float*)C)[(long)(row + r) * N + col] = val;
                else ((__bf16*)C)[(long)(row + r) * N + col] = (__bf16)val;
            }
        }
    }
}

// ---------------------------------------------------------------------------
// Flash attention (32x32 S^T / O^T, in-register P, single-barrier loop).
// BYTE-IDENTICAL to r11 (106.4 us) for clean attribution of pipeline changes.
// ---------------------------------------------------------------------------
__global__ __launch_bounds__(256, 3) void attn_kernel(
    const __bf16* __restrict__ Qg, const __bf16* __restrict__ Kg,
    const __bf16* __restrict__ Vg, __bf16* __restrict__ Og)
{
    const int bh = blockIdx.x;
    const int b = bh >> 4, h = bh & 15;
    const int q0 = blockIdx.y * 128;
    const int base = b * 2048 * 1024 + h * 64;
    const int tid = threadIdx.x;
    const int wave = tid >> 6, ln = tid & 63;
    const int l31 = ln & 31, hl = ln >> 5;    // lane-in-32, lane half
    const int h8 = hl * 8;

    __shared__ __bf16 Ks[2][64 * 64];     // 16 KB, double buffer, SW64 [j][k]
    __shared__ __bf16 VTs[2][64 * 64];    // 16 KB, double buffer, SW64 [d][j]

    // Q fragments (B-operand of S^T): lane n=q=l31, k = ks*16 + h8 + e
    bf16x8 qf[4];
    #pragma unroll
    for (int ks = 0; ks < 4; ks++)
        qf[ks] = *(const bf16x8*)&Qg[base + (q0 + wave * 32 + l31) * 1024 + ks * 16 + h8];

    const int kr = tid >> 3, kc = (tid & 7) << 3;   // K staging: rows kr, kr+32
    const int vr2 = (tid >> 3) * 2, vc = (tid & 7) << 3;  // V staging: row pair

    {   // tile 0 (published by the t=0 barrier)
        bf16x8 ka = *(const bf16x8*)&Kg[base + kr * 1024 + kc];
        bf16x8 kb = *(const bf16x8*)&Kg[base + (kr + 32) * 1024 + kc];
        bf16x8 va = *(const bf16x8*)&Vg[base + vr2 * 1024 + vc];
        bf16x8 vb = *(const bf16x8*)&Vg[base + (vr2 + 1) * 1024 + vc];
        *(bf16x8*)&Ks[0][SW64(kr, kc)] = ka;
        *(bf16x8*)&Ks[0][SW64(kr + 32, kc)] = kb;
        #pragma unroll
        for (int j = 0; j < 8; j++)
            *(unsigned int*)&VTs[0][SW64(vc + j, vr2)] = pack2(va[j], vb[j]);
    }

    floatx16 o_acc[2] = {};
    float m_i = -1e30f, l_i = 0.0f;

    for (int t = 0; t < 32; t++) {
        const int cur = t & 1, nxt = cur ^ 1;
        bf16x8 nka, nkb, nva, nvb;          // K/V(t+1) register prefetch
        if (t < 31) {
            const int kvn = (t + 1) * 64;
            nka = *(const bf16x8*)&Kg[base + (kvn + kr) * 1024 + kc];
            nkb = *(const bf16x8*)&Kg[base + (kvn + kr + 32) * 1024 + kc];
            nva = *(const bf16x8*)&Vg[base + (kvn + vr2) * 1024 + vc];
            nvb = *(const bf16x8*)&Vg[base + (kvn + vr2 + 1) * 1024 + vc];
        }
        __syncthreads();  // writes(t-1) -> nxt_{t-1}=cur visible; reads(t-1) drained

        // ---- S^T = K · Q^T: lane q=l31; j = (r&3)+8*(r>>2)+4*hl (+32 for s1)
        floatx16 sv[2] = {};
        #pragma unroll
        for (int ks = 0; ks < 4; ks++) {
            bf16x8 a0 = *(const bf16x8*)&Ks[cur][SW64(l31, ks * 16 + h8)];
            bf16x8 a1 = *(const bf16x8*)&Ks[cur][SW64(32 + l31, ks * 16 + h8)];
            sv[0] = __builtin_amdgcn_mfma_f32_32x32x16_bf16(a0, qf[ks], sv[0], 0, 0, 0);
            sv[1] = __builtin_amdgcn_mfma_f32_32x32x16_bf16(a1, qf[ks], sv[1], 0, 0, 0);
        }

        // ---- softmax for q=l31 over 64 j: own-32 tree + partner half
        float m8[8];
        #pragma unroll
        for (int r = 0; r < 8; r++)
            m8[r] = fmaxf(fmaxf(sv[0][r], sv[0][r + 8]), fmaxf(sv[1][r], sv[1][r + 8]));
        float mx = fmaxf(fmaxf(fmaxf(m8[0], m8[4]), fmaxf(m8[1], m8[5])),
                         fmaxf(fmaxf(m8[2], m8[6]), fmaxf(m8[3], m8[7])));
        mx = fmaxf(mx, __shfl_xor(mx, 32));

        if (__any(mx > m_i + 8.0f)) {       // defer-max: rescale only on big jumps
            float m_new = fmaxf(m_i, mx);
            float alpha = fast_exp2(m_i - m_new);
            m_i = m_new;
            l_i *= alpha;
            #pragma unroll
            for (int dt = 0; dt < 2; dt++)
                #pragma unroll
                for (int r = 0; r < 16; r++) o_acc[dt][r] *= alpha;
        }

        float p0[16], p1[16];
        #pragma unroll
        for (int r = 0; r < 16; r++) p0[r] = fast_exp2(sv[0][r] - m_i);
        #pragma unroll
        for (int r = 0; r < 16; r++) p1[r] = fast_exp2(sv[1][r] - m_i);
        float rsA = 0.f, rsB = 0.f, rsC = 0.f, rsD = 0.f;
        #pragma unroll
        for (int r = 0; r < 16; r += 4) {
            rsA += p0[r]; rsB += p0[r + 1]; rsC += p0[r + 2]; rsD += p0[r + 3];
            rsA += p1[r]; rsB += p1[r + 1]; rsC += p1[r + 2]; rsD += p1[r + 3];
        }
        float rs = (rsA + rsB) + (rsC + rsD);
        rs += __shfl_xor(rs, 32);
        l_i += rs;

        // ---- P -> bf16 B-frags in registers (pack pairs; cross-half exchange)
        bf16x8 pf0, pf1, pf2, pf3;
        {
            unsigned int A0 = pack_bf16(p0[0], p0[1]),  B0 = pack_bf16(p0[2], p0[3]);
            unsigned int C0 = pack_bf16(p0[4], p0[5]),  D0 = pack_bf16(p0[6], p0[7]);
            unsigned int A1 = pack_bf16(p0[8], p0[9]),  B1 = pack_bf16(p0[10], p0[11]);
            unsigned int C1 = pack_bf16(p0[12], p0[13]), D1 = pack_bf16(p0[14], p0[15]);
            xchg(A0, C0, hl); xchg(B0, D0, hl); xchg(A1, C1, hl); xchg(B1, D1, hl);
            pf0 = frag4(A0, B0, C0, D0);
            pf1 = frag4(A1, B1, C1, D1);
        }
        {
            unsigned int A0 = pack_bf16(p1[0], p1[1]),  B0 = pack_bf16(p1[2], p1[3]);
            unsigned int C0 = pack_bf16(p1[4], p1[5]),  D0 = pack_bf16(p1[6], p1[7]);
            unsigned int A1 = pack_bf16(p1[8], p1[9]),  B1 = pack_bf16(p1[10], p1[11]);
            unsigned int C1 = pack_bf16(p1[12], p1[13]), D1 = pack_bf16(p1[14], p1[15]);
            xchg(A0, C0, hl); xchg(B0, D0, hl); xchg(A1, C1, hl); xchg(B1, D1, hl);
            pf2 = frag4(A0, B0, C0, D0);
            pf3 = frag4(A1, B1, C1, D1);
        }

        if (t < 31) {     // K(t+1) -> other buffer; overlaps PV (no barrier)
            *(bf16x8*)&Ks[nxt][SW64(kr, kc)] = nka;
            *(bf16x8*)&Ks[nxt][SW64(kr + 32, kc)] = nkb;
        }

        // ---- O^T += V^T · P^T  (A = VTs rows b128, B = P-frags in regs)
        #pragma unroll
        for (int js = 0; js < 4; js++) {
            bf16x8 av0 = *(const bf16x8*)&VTs[cur][SW64(l31, js * 16 + h8)];
            bf16x8 av1 = *(const bf16x8*)&VTs[cur][SW64(32 + l31, js * 16 + h8)];
            bf16x8 pb = (js == 0) ? pf0 : (js == 1) ? pf1 : (js == 2) ? pf2 : pf3;
            o_acc[0] = __builtin_amdgcn_mfma_f32_32x32x16_bf16(av0, pb, o_acc[0], 0, 0, 0);
            o_acc[1] = __builtin_amdgcn_mfma_f32_32x32x16_bf16(av1, pb, o_acc[1], 0, 0, 0);
        }

        if (t < 31) {     // V(t+1) transpose store -> other buffer
            #pragma unroll
            for (int j = 0; j < 8; j++)
                *(unsigned int*)&VTs[nxt][SW64(vc + j, vr2)] = pack2(nva[j], nvb[j]);
        }
    }

    // ---- epilogue: O^T lane holds q=l31, d = dt*32 + 8g + 4*hl + e
    float inv = 1.0f / l_i;
    const int orow = q0 + wave * 32 + l31;
    #pragma unroll
    for (int dt = 0; dt < 2; dt++)
        #pragma unroll
        for (int g = 0; g < 4; g++) {
            bf16x4 ov;
            #pragma unroll
            for (int e = 0; e < 4; e++) ov[e] = (__bf16)(o_acc[dt][g * 4 + e] * inv);
            *(bf16x4*)&Og[base + orow * 1024 + dt * 32 + g * 8 + hl * 4] = ov;
        }
}

// ---------------------------------------------------------------------------
extern "C" void kernel_launch(void* const* d_in, const int* in_sizes, int n_in,
                              void* d_out, int out_size, void* d_ws, size_t ws_size,
                              hipStream_t stream)
{
    int* flag = (int*)d_ws;
    __bf16* cv = (__bf16*)((char*)d_ws + 256);

    // Region map (elem offsets into cv):
    //   0        z-bf16 [8192,1024]; reused as Ow after proj1 consumes it
    //   8388608  wq^T/wk^T/wv^T [64,1024] x3      (proj1 BT)
    //   8585216  fcq_w^T/fck_w^T/fcv_w^T [1024,64] x3 (proj2 BT)
    //   8781824  fco_w^T [1024,1024]               (proj3 BT)
    //   9830400  biases fcq_b|fck_b|fcv_b|fco_b (4x1024, consecutive)
    //   10485760 zb [8192,64] x3 (proj1 out)
    //   12582912 Qw, +8388608 Kw, +16777216 Vw
    const int Z = 0, WQT = 8388608, FCWT = 8585216, FCOWT = 8781824, BIAS = 9830400;
    __bf16* zb = cv + 10485760;
    __bf16* Qw = cv + 12582912;
    __bf16* Kw = Qw + 8388608;
    __bf16* Vw = Kw + 8388608;
    __bf16* Ow = cv + Z;        // z-bf16 region, dead after proj1

    detect_dtype<<<1, 256, 0, stream>>>((const unsigned short*)d_in[0], flag);

    MegaArgs ma;
    ma.z = d_in[0];
    ma.bias[0] = d_in[5]; ma.bias[1] = d_in[7]; ma.bias[2] = d_in[9]; ma.bias[3] = d_in[11];
    ma.w[0] = d_in[1]; ma.w[1] = d_in[2]; ma.w[2] = d_in[3];          // wq wk wv [1024,64]
    ma.w[3] = d_in[4]; ma.w[4] = d_in[6]; ma.w[5] = d_in[8];          // fc*_w [64,1024]
    ma.w[6] = d_in[10];                                               // fco_w [1024,1024]
    mega_convert<<<dim3(4450, 1), 256, 0, stream>>>(ma, cv, flag);

    // proj1: zb[8192,64]x3 = z @ w{q,k,v}   (BT = w^T [64,1024])
    gemm64<<<dim3(128, 1, 3), 256, 0, stream>>>(
        cv + Z, cv + WQT, cv + WQT + 65536, cv + WQT + 131072,
        zb, zb + 524288, zb + 1048576, 1024);

    const float QSC = 0.125f * 1.44269504088896f;  // fold 1/sqrt(dk) * log2(e) into Q
    // proj2: Q/K/V[8192,1024] = zb @ fc*_w + b
    gemm128<<<dim3(64, 8, 3), 256, 0, stream>>>(
        zb, zb + 524288, zb + 1048576,
        cv + FCWT, cv + FCWT + 65536, cv + FCWT + 131072,
        cv + BIAS, cv + BIAS + 1024, cv + BIAS + 2048,
        Qw, Kw, Vw, 8192, 1024, 64, nullptr,
        QSC, 1.0f, 1.0f);

    attn_kernel<<<dim3(64, 16), 256, 0, stream>>>(Qw, Kw, Vw, Ow);

    // proj3: out[8192,1024] = Ow @ fco_w + b
    gemm128<<<dim3(64, 8, 1), 256, 0, stream>>>(
        Ow, Ow, Ow, cv + FCOWT, cv + FCOWT, cv + FCOWT,
        cv + BIAS + 3072, cv + BIAS + 3072, cv + BIAS + 3072,
        d_out, d_out, d_out, 8192, 1024, 1024, flag,
        1.0f, 1.0f, 1.0f);
}